// Round 1
// 572.156 us; speedup vs baseline: 1.1323x; 1.1323x over previous
//
#include <hip/hip_runtime.h>
#include <hip/hip_bf16.h>
#include <math.h>

#define N_NODES 100000
#define F_IN 512
#define H_DIM 16
#define C_DIM 40

#define BSHIFT 9                       // 512 nodes per bucket
#define BNODES 512
#define NBUCK 196                      // ceil(100000 / 512)
#define CHUNK 8192                     // edges per partition block
#define SRC_MASK 0x1FFFF               // 17 bits (N < 131072)

// ---------------- bucket histogram (196 bins) — replaces 100k-bin global-atomic hist ----------------

__global__ void __launch_bounds__(256) bhist_kernel(const int* __restrict__ dst,
                                                    int* __restrict__ BC, int E) {
    __shared__ int cnt[NBUCK];
    int start = blockIdx.x * CHUNK;
    int end = start + CHUNK < E ? start + CHUNK : E;
    for (int i = threadIdx.x; i < NBUCK; i += 256) cnt[i] = 0;
    __syncthreads();
    for (int i = start + threadIdx.x; i < end; i += 256)
        atomicAdd(&cnt[dst[i] >> BSHIFT], 1);
    __syncthreads();
    for (int i = threadIdx.x; i < NBUCK; i += 256) {
        int c = cnt[i];
        if (c) atomicAdd(&BC[i], c);
    }
}

// ---------------- scan of 196 bucket counts -> BO / cursor; R[N]=E ----------------

__global__ void __launch_bounds__(256) bscan_kernel(const int* __restrict__ BC,
                                                    int* __restrict__ BO,
                                                    int* __restrict__ cursor,
                                                    int* __restrict__ R, int E, int N) {
    __shared__ int buf[2][256];
    int tid = threadIdx.x;
    int v = (tid < NBUCK) ? BC[tid] : 0;
    int cur = 0;
    buf[0][tid] = v;
    __syncthreads();
    for (int off = 1; off < 256; off <<= 1) {
        int t = buf[cur][tid] + ((tid >= off) ? buf[cur][tid - off] : 0);
        cur ^= 1;
        buf[cur][tid] = t;
        __syncthreads();
    }
    int excl = buf[cur][tid] - v;                 // exclusive prefix
    if (tid <= NBUCK) {                           // tid==NBUCK -> total == E
        BO[tid] = excl;
        if (tid < NBUCK) cursor[tid] = excl;
    }
    if (tid == 0) R[N] = E;
}

// ---------------- radix partition by dst bucket; packed = (local_dst<<17)|src ----------------

__global__ void __launch_bounds__(256) partition_kernel(const int* __restrict__ src,
                                                        const int* __restrict__ dst,
                                                        int* __restrict__ cursor,
                                                        int* __restrict__ packed, int E) {
    __shared__ int cnt[NBUCK];
    __shared__ int base[NBUCK];
    int start = blockIdx.x * CHUNK;
    int end = start + CHUNK < E ? start + CHUNK : E;
    for (int i = threadIdx.x; i < NBUCK; i += 256) cnt[i] = 0;
    __syncthreads();
    for (int i = start + threadIdx.x; i < end; i += 256)
        atomicAdd(&cnt[dst[i] >> BSHIFT], 1);
    __syncthreads();
    for (int i = threadIdx.x; i < NBUCK; i += 256) {
        int c = cnt[i];
        base[i] = c ? atomicAdd(&cursor[i], c) : 0;
        cnt[i] = 0;  // reuse as local position
    }
    __syncthreads();
    for (int i = start + threadIdx.x; i < end; i += 256) {
        int d = dst[i];
        int b = d >> BSHIFT;
        int p = base[b] + atomicAdd(&cnt[b], 1);
        packed[p] = ((d & (BNODES - 1)) << 17) | src[i];
    }
}

// ---------------- per-bucket: degree hist + scan -> R/dinv, then counting scatter -> eidx ----------------

__global__ void __launch_bounds__(512) sort2_kernel(const int* __restrict__ BO,
                                                    const int* __restrict__ packed,
                                                    int* __restrict__ R,
                                                    float* __restrict__ dinv,
                                                    int* __restrict__ eidx, int N) {
    __shared__ int cnt[BNODES];
    __shared__ int buf[2][BNODES];
    int b = blockIdx.x;
    int tid = threadIdx.x;
    int lo = BO[b], hi = BO[b + 1];
    cnt[tid] = 0;
    __syncthreads();
    // pass 1: per-node degree histogram in LDS
    for (int e = lo + tid; e < hi; e += 512)
        atomicAdd(&cnt[packed[e] >> 17], 1);
    __syncthreads();
    int deg = cnt[tid];
    // 512-wide Hillis-Steele inclusive scan -> exclusive offsets
    int cur = 0;
    buf[0][tid] = deg;
    __syncthreads();
    for (int off = 1; off < 512; off <<= 1) {
        int t = buf[cur][tid] + ((tid >= off) ? buf[cur][tid - off] : 0);
        cur ^= 1;
        buf[cur][tid] = t;
        __syncthreads();
    }
    int excl = lo + buf[cur][tid] - deg;          // global CSR offset for this node
    int n = (b << BSHIFT) + tid;
    if (n < N) {
        R[n] = excl;
        dinv[n] = rsqrtf((float)(deg + 1));       // +1 = self-loop
    }
    cnt[tid] = excl;                              // reuse as per-node cursor
    __syncthreads();
    // pass 2: counting scatter; writes stay inside [BO[b], BO[b+1]) — L2-local
    for (int e = lo + tid; e < hi; e += 512) {
        int p = packed[e];
        int pos = atomicAdd(&cnt[p >> 17], 1);
        eidx[pos] = p & SRC_MASK;
    }
}

// ---------------- GEMM1: g1 = (x @ W1) * dinv, 1 row per thread ----------------

__global__ void __launch_bounds__(256) gemm1_kernel(const float* __restrict__ x,
                                                    const float* __restrict__ W1,
                                                    const float* __restrict__ dinv,
                                                    float* __restrict__ g1, int N) {
    __shared__ float w[F_IN * H_DIM];  // 32 KB
    {
        float4* w4s = (float4*)w;
        const float4* W4 = (const float4*)W1;
        for (int i = threadIdx.x; i < F_IN * H_DIM / 4; i += 256) w4s[i] = W4[i];
    }
    __syncthreads();
    int row = blockIdx.x * 256 + threadIdx.x;
    if (row >= N) return;
    const float4* xr = (const float4*)(x + (size_t)row * F_IN);
    float acc[H_DIM];
#pragma unroll
    for (int k = 0; k < H_DIM; k++) acc[k] = 0.0f;
    const float4* w4 = (const float4*)w;
    for (int f4 = 0; f4 < F_IN / 4; ++f4) {
        float4 xv = xr[f4];
        float xs[4] = {xv.x, xv.y, xv.z, xv.w};
#pragma unroll
        for (int q = 0; q < 4; q++) {
            float wq[H_DIM];
#pragma unroll
            for (int p = 0; p < 4; p++) *(float4*)&wq[4 * p] = w4[(f4 * 4 + q) * 4 + p];
            float s = xs[q];
#pragma unroll
            for (int k = 0; k < H_DIM; k++) acc[k] += s * wq[k];
        }
    }
    float di = dinv[row];
    float4* o = (float4*)(g1 + (size_t)row * H_DIM);
#pragma unroll
    for (int p = 0; p < 4; p++)
        o[p] = make_float4(acc[4 * p] * di, acc[4 * p + 1] * di,
                           acc[4 * p + 2] * di, acc[4 * p + 3] * di);
}

// ---------------- node-parallel CSR aggregation, register accumulate, unroll 8 ----------------

// layer 1: g2 = dinv * relu(dinv*(sum + self) + b1)
__global__ void __launch_bounds__(256) agg1_kernel(const int* __restrict__ R,
                                                   const int* __restrict__ eidx,
                                                   const float* __restrict__ g1,
                                                   const float* __restrict__ dinv,
                                                   const float* __restrict__ b1,
                                                   float* __restrict__ g2, int N) {
    int t = blockIdx.x * 256 + threadIdx.x;
    int n = t >> 4;
    if (n >= N) return;
    int k = t & 15;
    int lo = R[n], hi = R[n + 1];
    float sum = g1[t];  // self-loop (g1 = dinv*h1)
    int e = lo;
    for (; e + 8 <= hi; e += 8) {
        int s[8];
        float v[8];
#pragma unroll
        for (int u = 0; u < 8; u++) s[u] = eidx[e + u];
#pragma unroll
        for (int u = 0; u < 8; u++) v[u] = g1[s[u] * H_DIM + k];
#pragma unroll
        for (int u = 0; u < 8; u++) sum += v[u];
    }
    for (; e < hi; ++e) sum += g1[eidx[e] * H_DIM + k];
    float di = dinv[n];
    g2[t] = di * fmaxf(di * sum + b1[k], 0.0f);
}

// layer 2: s2 = sum + self (dinv, W2, b2 applied in final)
__global__ void __launch_bounds__(256) agg2_kernel(const int* __restrict__ R,
                                                   const int* __restrict__ eidx,
                                                   const float* __restrict__ g2,
                                                   float* __restrict__ s2, int N) {
    int t = blockIdx.x * 256 + threadIdx.x;
    int n = t >> 4;
    if (n >= N) return;
    int k = t & 15;
    int lo = R[n], hi = R[n + 1];
    float sum = g2[t];
    int e = lo;
    for (; e + 8 <= hi; e += 8) {
        int s[8];
        float v[8];
#pragma unroll
        for (int u = 0; u < 8; u++) s[u] = eidx[e + u];
#pragma unroll
        for (int u = 0; u < 8; u++) v[u] = g2[s[u] * H_DIM + k];
#pragma unroll
        for (int u = 0; u < 8; u++) sum += v[u];
    }
    for (; e < hi; ++e) sum += g2[eidx[e] * H_DIM + k];
    s2[t] = sum;
}

// ---------------- final: v = dinv*s2; logits = v@W2 + b2; log_softmax; coalesced writes ----------------

__global__ void __launch_bounds__(256) final_kernel(const float* __restrict__ s2,
                                                    const float* __restrict__ dinv,
                                                    const float* __restrict__ W2,
                                                    const float* __restrict__ b2,
                                                    float* __restrict__ out, int N) {
    __shared__ float w2s[H_DIM * C_DIM];
    __shared__ float b2s[C_DIM];
    __shared__ float stage[256 * 41];
    for (int i = threadIdx.x; i < H_DIM * C_DIM; i += 256) w2s[i] = W2[i];
    if (threadIdx.x < C_DIM) b2s[threadIdx.x] = b2[threadIdx.x];
    __syncthreads();
    int n = blockIdx.x * 256 + threadIdx.x;
    int cn = n < N ? n : 0;
    float di = dinv[cn];
    float v[H_DIM];
    const float4* sv = (const float4*)(s2 + (size_t)cn * H_DIM);
#pragma unroll
    for (int p = 0; p < 4; p++) {
        float4 t = sv[p];
        v[4 * p] = di * t.x; v[4 * p + 1] = di * t.y;
        v[4 * p + 2] = di * t.z; v[4 * p + 3] = di * t.w;
    }
    float lg[C_DIM];
    float m = -1e30f;
    for (int c = 0; c < C_DIM; c++) {
        float a = b2s[c];
#pragma unroll
        for (int k = 0; k < H_DIM; k++) a += v[k] * w2s[k * C_DIM + c];
        lg[c] = a;
        m = fmaxf(m, a);
    }
    float ssum = 0.0f;
    for (int c = 0; c < C_DIM; c++) ssum += __expf(lg[c] - m);
    float lse = m + __logf(ssum);

    size_t base = (size_t)blockIdx.x * 256 * C_DIM;
    size_t lim = (size_t)N * C_DIM;
    for (int c = 0; c < C_DIM; c++) stage[threadIdx.x * 41 + c] = lg[c] - lse;
    __syncthreads();
    for (int i = threadIdx.x; i < 256 * C_DIM; i += 256) {
        int nn = i / C_DIM, c = i - nn * C_DIM;
        size_t g = base + i;
        if (g < lim) out[g] = stage[nn * 41 + c];
    }
    __syncthreads();
    for (int c = 0; c < C_DIM; c++) stage[threadIdx.x * 41 + c] = lg[c];
    __syncthreads();
    for (int i = threadIdx.x; i < 256 * C_DIM; i += 256) {
        int nn = i / C_DIM, c = i - nn * C_DIM;
        size_t g = base + i;
        if (g < lim) out[lim + g] = stage[nn * 41 + c];
    }
}

// ---------------- launch ----------------

extern "C" void kernel_launch(void* const* d_in, const int* in_sizes, int n_in,
                              void* d_out, int out_size, void* d_ws, size_t ws_size,
                              hipStream_t stream) {
    const float* x  = (const float*)d_in[0];
    const int* ei   = (const int*)d_in[1];
    const float* W1 = (const float*)d_in[2];
    const float* b1 = (const float*)d_in[3];
    const float* W2 = (const float*)d_in[4];
    const float* b2 = (const float*)d_in[5];
    float* out = (float*)d_out;

    const int N = N_NODES;
    const int E = in_sizes[1] / 2;
    const int* src = ei;
    const int* dst = ei + E;

    // ws layout (ints): R[N+16] | BC[512] | BO[256] | cursor[256] | dinv[N+16] | eidx[E] |
    //                   union{ packed[E]  |  g1[16N] + g2[16N] }     (~26.4 MB total)
    int* R      = (int*)d_ws;                 // CSR node offsets (R[N] = E)
    int* BC     = R + 100016;                 // bucket counts
    int* BO     = BC + 512;                   // bucket offsets (exclusive scan)
    int* cursor = BO + 256;
    float* dinv = (float*)(cursor + 256);
    int* eidx   = (int*)(dinv + 100016);
    int* packed = eidx + E;                   // dead after sort2_kernel
    float* g1   = (float*)packed;             // reuses packed region
    float* g2   = g1 + 16 * N;
    float* s2   = g1;                         // g1 dead after agg1

    const int NB = (N + 255) / 256;  // 391
    const int NCH = (E + CHUNK - 1) / CHUNK;

    hipMemsetAsync(BC, 0, NBUCK * sizeof(int), stream);
    bhist_kernel<<<NCH, 256, 0, stream>>>(dst, BC, E);
    bscan_kernel<<<1, 256, 0, stream>>>(BC, BO, cursor, R, E, N);
    partition_kernel<<<NCH, 256, 0, stream>>>(src, dst, cursor, packed, E);
    sort2_kernel<<<NBUCK, 512, 0, stream>>>(BO, packed, R, dinv, eidx, N);

    gemm1_kernel<<<NB, 256, 0, stream>>>(x, W1, dinv, g1, N);
    agg1_kernel<<<(N * 16 + 255) / 256, 256, 0, stream>>>(R, eidx, g1, dinv, b1, g2, N);
    agg2_kernel<<<(N * 16 + 255) / 256, 256, 0, stream>>>(R, eidx, g2, s2, N);
    final_kernel<<<NB, 256, 0, stream>>>(s2, dinv, W2, b2, out, N);
}

// Round 2
// 557.927 us; speedup vs baseline: 1.1612x; 1.0255x over previous
//
#include <hip/hip_runtime.h>
#include <hip/hip_bf16.h>
#include <math.h>

#define N_NODES 100000
#define F_IN 512
#define H_DIM 16
#define C_DIM 40

#define BSHIFT 9                       // 512 nodes per bucket
#define BNODES 512
#define NBUCK 196                      // ceil(100000 / 512)
#define CHUNK 8192                     // edges per partition block
#define SRC_MASK 0x1FFFF               // 17 bits (N < 131072)

// ---------------- bucket histogram (196 bins) ----------------

__global__ void __launch_bounds__(256) bhist_kernel(const int* __restrict__ dst,
                                                    int* __restrict__ BC, int E) {
    __shared__ int cnt[NBUCK];
    int start = blockIdx.x * CHUNK;
    int end = start + CHUNK < E ? start + CHUNK : E;
    for (int i = threadIdx.x; i < NBUCK; i += 256) cnt[i] = 0;
    __syncthreads();
    for (int i = start + threadIdx.x; i < end; i += 256)
        atomicAdd(&cnt[dst[i] >> BSHIFT], 1);
    __syncthreads();
    for (int i = threadIdx.x; i < NBUCK; i += 256) {
        int c = cnt[i];
        if (c) atomicAdd(&BC[i], c);
    }
}

// ---------------- scan of 196 bucket counts -> BO / cursor; R[N]=E ----------------

__global__ void __launch_bounds__(256) bscan_kernel(const int* __restrict__ BC,
                                                    int* __restrict__ BO,
                                                    int* __restrict__ cursor,
                                                    int* __restrict__ R, int E, int N) {
    __shared__ int buf[2][256];
    int tid = threadIdx.x;
    int v = (tid < NBUCK) ? BC[tid] : 0;
    int cur = 0;
    buf[0][tid] = v;
    __syncthreads();
    for (int off = 1; off < 256; off <<= 1) {
        int t = buf[cur][tid] + ((tid >= off) ? buf[cur][tid - off] : 0);
        cur ^= 1;
        buf[cur][tid] = t;
        __syncthreads();
    }
    int excl = buf[cur][tid] - v;                 // exclusive prefix
    if (tid <= NBUCK) {                           // tid==NBUCK -> total == E
        BO[tid] = excl;
        if (tid < NBUCK) cursor[tid] = excl;
    }
    if (tid == 0) R[N] = E;
}

// ---------------- radix partition by dst bucket; packed = (local_dst<<17)|src ----------------

__global__ void __launch_bounds__(256) partition_kernel(const int* __restrict__ src,
                                                        const int* __restrict__ dst,
                                                        int* __restrict__ cursor,
                                                        int* __restrict__ packed, int E) {
    __shared__ int cnt[NBUCK];
    __shared__ int base[NBUCK];
    int start = blockIdx.x * CHUNK;
    int end = start + CHUNK < E ? start + CHUNK : E;
    for (int i = threadIdx.x; i < NBUCK; i += 256) cnt[i] = 0;
    __syncthreads();
    for (int i = start + threadIdx.x; i < end; i += 256)
        atomicAdd(&cnt[dst[i] >> BSHIFT], 1);
    __syncthreads();
    for (int i = threadIdx.x; i < NBUCK; i += 256) {
        int c = cnt[i];
        base[i] = c ? atomicAdd(&cursor[i], c) : 0;
        cnt[i] = 0;  // reuse as local position
    }
    __syncthreads();
    for (int i = start + threadIdx.x; i < end; i += 256) {
        int d = dst[i];
        int b = d >> BSHIFT;
        int p = base[b] + atomicAdd(&cnt[b], 1);
        packed[p] = ((d & (BNODES - 1)) << 17) | src[i];
    }
}

// ---------------- per-bucket: degree hist + scan -> R/dinv, then counting scatter -> eidx ----------------

__global__ void __launch_bounds__(512) sort2_kernel(const int* __restrict__ BO,
                                                    const int* __restrict__ packed,
                                                    int* __restrict__ R,
                                                    float* __restrict__ dinv,
                                                    int* __restrict__ eidx, int N) {
    __shared__ int cnt[BNODES];
    __shared__ int buf[2][BNODES];
    int b = blockIdx.x;
    int tid = threadIdx.x;
    int lo = BO[b], hi = BO[b + 1];
    cnt[tid] = 0;
    __syncthreads();
    // pass 1: per-node degree histogram in LDS
    for (int e = lo + tid; e < hi; e += 512)
        atomicAdd(&cnt[packed[e] >> 17], 1);
    __syncthreads();
    int deg = cnt[tid];
    // 512-wide Hillis-Steele inclusive scan -> exclusive offsets
    int cur = 0;
    buf[0][tid] = deg;
    __syncthreads();
    for (int off = 1; off < 512; off <<= 1) {
        int t = buf[cur][tid] + ((tid >= off) ? buf[cur][tid - off] : 0);
        cur ^= 1;
        buf[cur][tid] = t;
        __syncthreads();
    }
    int excl = lo + buf[cur][tid] - deg;          // global CSR offset for this node
    int n = (b << BSHIFT) + tid;
    if (n < N) {
        R[n] = excl;
        dinv[n] = rsqrtf((float)(deg + 1));       // +1 = self-loop
    }
    cnt[tid] = excl;                              // reuse as per-node cursor
    __syncthreads();
    // pass 2: counting scatter; writes stay inside [BO[b], BO[b+1]) — L2-local
    for (int e = lo + tid; e < hi; e += 512) {
        int p = packed[e];
        int pos = atomicAdd(&cnt[p >> 17], 1);
        eidx[pos] = p & SRC_MASK;
    }
}

// ---------------- GEMM1: g1 = (x @ W1) * dinv ----------------
// Coalesced LDS staging: per 32-float K-chunk, 8 lanes load 128B contiguous per row
// (float4 each), stored at LDS stride 33 (read bank = (tid+j)%32 -> conflict-free).

__global__ void __launch_bounds__(256) gemm1_kernel(const float* __restrict__ x,
                                                    const float* __restrict__ W1,
                                                    const float* __restrict__ dinv,
                                                    float* __restrict__ g1, int N) {
    __shared__ float w[F_IN * H_DIM];   // 32 KB
    __shared__ float xs[256 * 33];      // 33 KB staged x tile, stride 33
    {
        float4* w4s = (float4*)w;
        const float4* W4 = (const float4*)W1;
        for (int i = threadIdx.x; i < F_IN * H_DIM / 4; i += 256) w4s[i] = W4[i];
    }
    int rowbase = blockIdx.x * 256;
    int row = rowbase + threadIdx.x;
    float acc[H_DIM];
#pragma unroll
    for (int k = 0; k < H_DIM; k++) acc[k] = 0.0f;

    int r0 = threadIdx.x >> 3;          // 8 lanes per row
    int seg = threadIdx.x & 7;          // float4 segment within the 32-float chunk

    for (int kc = 0; kc < F_IN / 32; ++kc) {
        __syncthreads();                // xs free from previous chunk's readers
#pragma unroll
        for (int rep = 0; rep < 8; ++rep) {
            int r = r0 + rep * 32;
            int gr = rowbase + r;
            float4 v = make_float4(0.f, 0.f, 0.f, 0.f);
            if (gr < N) v = *(const float4*)(x + (size_t)gr * F_IN + kc * 32 + seg * 4);
            float* dp = &xs[r * 33 + seg * 4];
            dp[0] = v.x; dp[1] = v.y; dp[2] = v.z; dp[3] = v.w;
        }
        __syncthreads();
        const float* xr = &xs[threadIdx.x * 33];
        const float* wk = &w[kc * 32 * H_DIM];
#pragma unroll
        for (int j = 0; j < 32; ++j) {
            float s = xr[j];
            const float4* wj = (const float4*)&wk[j * H_DIM];
#pragma unroll
            for (int p = 0; p < 4; p++) {
                float4 wv = wj[p];
                acc[4 * p + 0] += s * wv.x;
                acc[4 * p + 1] += s * wv.y;
                acc[4 * p + 2] += s * wv.z;
                acc[4 * p + 3] += s * wv.w;
            }
        }
    }
    if (row < N) {
        float di = dinv[row];
        float4* o = (float4*)(g1 + (size_t)row * H_DIM);
#pragma unroll
        for (int p = 0; p < 4; p++)
            o[p] = make_float4(acc[4 * p] * di, acc[4 * p + 1] * di,
                               acc[4 * p + 2] * di, acc[4 * p + 3] * di);
    }
}

// ---------------- node-parallel CSR aggregation, register accumulate, unroll 8 ----------------

// layer 1: g2 = dinv * relu(dinv*(sum + self) + b1)
__global__ void __launch_bounds__(256) agg1_kernel(const int* __restrict__ R,
                                                   const int* __restrict__ eidx,
                                                   const float* __restrict__ g1,
                                                   const float* __restrict__ dinv,
                                                   const float* __restrict__ b1,
                                                   float* __restrict__ g2, int N) {
    int t = blockIdx.x * 256 + threadIdx.x;
    int n = t >> 4;
    if (n >= N) return;
    int k = t & 15;
    int lo = R[n], hi = R[n + 1];
    float sum = g1[t];  // self-loop (g1 = dinv*h1)
    int e = lo;
    for (; e + 8 <= hi; e += 8) {
        int s[8];
        float v[8];
#pragma unroll
        for (int u = 0; u < 8; u++) s[u] = eidx[e + u];
#pragma unroll
        for (int u = 0; u < 8; u++) v[u] = g1[s[u] * H_DIM + k];
#pragma unroll
        for (int u = 0; u < 8; u++) sum += v[u];
    }
    for (; e < hi; ++e) sum += g1[eidx[e] * H_DIM + k];
    float di = dinv[n];
    g2[t] = di * fmaxf(di * sum + b1[k], 0.0f);
}

// layer 2: s2 = sum + self (dinv, W2, b2 applied in final)
__global__ void __launch_bounds__(256) agg2_kernel(const int* __restrict__ R,
                                                   const int* __restrict__ eidx,
                                                   const float* __restrict__ g2,
                                                   float* __restrict__ s2, int N) {
    int t = blockIdx.x * 256 + threadIdx.x;
    int n = t >> 4;
    if (n >= N) return;
    int k = t & 15;
    int lo = R[n], hi = R[n + 1];
    float sum = g2[t];
    int e = lo;
    for (; e + 8 <= hi; e += 8) {
        int s[8];
        float v[8];
#pragma unroll
        for (int u = 0; u < 8; u++) s[u] = eidx[e + u];
#pragma unroll
        for (int u = 0; u < 8; u++) v[u] = g2[s[u] * H_DIM + k];
#pragma unroll
        for (int u = 0; u < 8; u++) sum += v[u];
    }
    for (; e < hi; ++e) sum += g2[eidx[e] * H_DIM + k];
    s2[t] = sum;
}

// ---------------- final: v = dinv*s2; logits = v@W2 + b2; log_softmax; coalesced writes ----------------

__global__ void __launch_bounds__(256) final_kernel(const float* __restrict__ s2,
                                                    const float* __restrict__ dinv,
                                                    const float* __restrict__ W2,
                                                    const float* __restrict__ b2,
                                                    float* __restrict__ out, int N) {
    __shared__ float w2s[H_DIM * C_DIM];
    __shared__ float b2s[C_DIM];
    __shared__ float stage[256 * 41];
    for (int i = threadIdx.x; i < H_DIM * C_DIM; i += 256) w2s[i] = W2[i];
    if (threadIdx.x < C_DIM) b2s[threadIdx.x] = b2[threadIdx.x];
    __syncthreads();
    int n = blockIdx.x * 256 + threadIdx.x;
    int cn = n < N ? n : 0;
    float di = dinv[cn];
    float v[H_DIM];
    const float4* sv = (const float4*)(s2 + (size_t)cn * H_DIM);
#pragma unroll
    for (int p = 0; p < 4; p++) {
        float4 t = sv[p];
        v[4 * p] = di * t.x; v[4 * p + 1] = di * t.y;
        v[4 * p + 2] = di * t.z; v[4 * p + 3] = di * t.w;
    }
    float lg[C_DIM];
    float m = -1e30f;
    for (int c = 0; c < C_DIM; c++) {
        float a = b2s[c];
#pragma unroll
        for (int k = 0; k < H_DIM; k++) a += v[k] * w2s[k * C_DIM + c];
        lg[c] = a;
        m = fmaxf(m, a);
    }
    float ssum = 0.0f;
    for (int c = 0; c < C_DIM; c++) ssum += __expf(lg[c] - m);
    float lse = m + __logf(ssum);

    size_t base = (size_t)blockIdx.x * 256 * C_DIM;
    size_t lim = (size_t)N * C_DIM;
    for (int c = 0; c < C_DIM; c++) stage[threadIdx.x * 41 + c] = lg[c] - lse;
    __syncthreads();
    for (int i = threadIdx.x; i < 256 * C_DIM; i += 256) {
        int nn = i / C_DIM, c = i - nn * C_DIM;
        size_t g = base + i;
        if (g < lim) out[g] = stage[nn * 41 + c];
    }
    __syncthreads();
    for (int c = 0; c < C_DIM; c++) stage[threadIdx.x * 41 + c] = lg[c];
    __syncthreads();
    for (int i = threadIdx.x; i < 256 * C_DIM; i += 256) {
        int nn = i / C_DIM, c = i - nn * C_DIM;
        size_t g = base + i;
        if (g < lim) out[lim + g] = stage[nn * 41 + c];
    }
}

// ---------------- launch ----------------

extern "C" void kernel_launch(void* const* d_in, const int* in_sizes, int n_in,
                              void* d_out, int out_size, void* d_ws, size_t ws_size,
                              hipStream_t stream) {
    const float* x  = (const float*)d_in[0];
    const int* ei   = (const int*)d_in[1];
    const float* W1 = (const float*)d_in[2];
    const float* b1 = (const float*)d_in[3];
    const float* W2 = (const float*)d_in[4];
    const float* b2 = (const float*)d_in[5];
    float* out = (float*)d_out;

    const int N = N_NODES;
    const int E = in_sizes[1] / 2;
    const int* src = ei;
    const int* dst = ei + E;

    // ws layout (ints): R[N+16] | BC[512] | BO[256] | cursor[256] | dinv[N+16] | eidx[E] |
    //                   union{ packed[E]  |  g1[16N] + g2[16N] }     (~26.4 MB total)
    int* R      = (int*)d_ws;                 // CSR node offsets (R[N] = E)
    int* BC     = R + 100016;                 // bucket counts
    int* BO     = BC + 512;                   // bucket offsets (exclusive scan)
    int* cursor = BO + 256;
    float* dinv = (float*)(cursor + 256);
    int* eidx   = (int*)(dinv + 100016);
    int* packed = eidx + E;                   // dead after sort2_kernel
    float* g1   = (float*)packed;             // reuses packed region
    float* g2   = g1 + 16 * N;
    float* s2   = g1;                         // g1 dead after agg1

    const int NB = (N + 255) / 256;  // 391
    const int NCH = (E + CHUNK - 1) / CHUNK;

    hipMemsetAsync(BC, 0, NBUCK * sizeof(int), stream);
    bhist_kernel<<<NCH, 256, 0, stream>>>(dst, BC, E);
    bscan_kernel<<<1, 256, 0, stream>>>(BC, BO, cursor, R, E, N);
    partition_kernel<<<NCH, 256, 0, stream>>>(src, dst, cursor, packed, E);
    sort2_kernel<<<NBUCK, 512, 0, stream>>>(BO, packed, R, dinv, eidx, N);

    gemm1_kernel<<<NB, 256, 0, stream>>>(x, W1, dinv, g1, N);
    agg1_kernel<<<(N * 16 + 255) / 256, 256, 0, stream>>>(R, eidx, g1, dinv, b1, g2, N);
    agg2_kernel<<<(N * 16 + 255) / 256, 256, 0, stream>>>(R, eidx, g2, s2, N);
    final_kernel<<<NB, 256, 0, stream>>>(s2, dinv, W2, b2, out, N);
}

// Round 3
// 542.887 us; speedup vs baseline: 1.1933x; 1.0277x over previous
//
#include <hip/hip_runtime.h>
#include <hip/hip_bf16.h>
#include <math.h>

#define N_NODES 100000
#define F_IN 512
#define H_DIM 16
#define C_DIM 40

#define BSHIFT 9                       // 512 nodes per bucket
#define BNODES 512
#define NBUCK 196                      // ceil(100000 / 512)
#define CHUNK 8192                     // edges per partition block
#define SRC_MASK 0x1FFFF               // 17 bits (N < 131072)

// ---------------- bucket histogram (196 bins) ----------------

__global__ void __launch_bounds__(256) bhist_kernel(const int* __restrict__ dst,
                                                    int* __restrict__ BC, int E) {
    __shared__ int cnt[NBUCK];
    int start = blockIdx.x * CHUNK;
    int end = start + CHUNK < E ? start + CHUNK : E;
    for (int i = threadIdx.x; i < NBUCK; i += 256) cnt[i] = 0;
    __syncthreads();
    for (int i = start + threadIdx.x; i < end; i += 256)
        atomicAdd(&cnt[dst[i] >> BSHIFT], 1);
    __syncthreads();
    for (int i = threadIdx.x; i < NBUCK; i += 256) {
        int c = cnt[i];
        if (c) atomicAdd(&BC[i], c);
    }
}

// ---------------- scan of 196 bucket counts -> BO / cursor; R[N]=E ----------------

__global__ void __launch_bounds__(256) bscan_kernel(const int* __restrict__ BC,
                                                    int* __restrict__ BO,
                                                    int* __restrict__ cursor,
                                                    int* __restrict__ R, int E, int N) {
    __shared__ int buf[2][256];
    int tid = threadIdx.x;
    int v = (tid < NBUCK) ? BC[tid] : 0;
    int cur = 0;
    buf[0][tid] = v;
    __syncthreads();
    for (int off = 1; off < 256; off <<= 1) {
        int t = buf[cur][tid] + ((tid >= off) ? buf[cur][tid - off] : 0);
        cur ^= 1;
        buf[cur][tid] = t;
        __syncthreads();
    }
    int excl = buf[cur][tid] - v;                 // exclusive prefix
    if (tid <= NBUCK) {                           // tid==NBUCK -> total == E
        BO[tid] = excl;
        if (tid < NBUCK) cursor[tid] = excl;
    }
    if (tid == 0) R[N] = E;
}

// ---------------- radix partition by dst bucket; packed = (local_dst<<17)|src ----------------

__global__ void __launch_bounds__(256) partition_kernel(const int* __restrict__ src,
                                                        const int* __restrict__ dst,
                                                        int* __restrict__ cursor,
                                                        int* __restrict__ packed, int E) {
    __shared__ int cnt[NBUCK];
    __shared__ int base[NBUCK];
    int start = blockIdx.x * CHUNK;
    int end = start + CHUNK < E ? start + CHUNK : E;
    for (int i = threadIdx.x; i < NBUCK; i += 256) cnt[i] = 0;
    __syncthreads();
    for (int i = start + threadIdx.x; i < end; i += 256)
        atomicAdd(&cnt[dst[i] >> BSHIFT], 1);
    __syncthreads();
    for (int i = threadIdx.x; i < NBUCK; i += 256) {
        int c = cnt[i];
        base[i] = c ? atomicAdd(&cursor[i], c) : 0;
        cnt[i] = 0;  // reuse as local position
    }
    __syncthreads();
    for (int i = start + threadIdx.x; i < end; i += 256) {
        int d = dst[i];
        int b = d >> BSHIFT;
        int p = base[b] + atomicAdd(&cnt[b], 1);
        packed[p] = ((d & (BNODES - 1)) << 17) | src[i];
    }
}

// ---------------- per-bucket: degree hist + scan -> R/dinv, then counting scatter -> eidx ----------------

__global__ void __launch_bounds__(512) sort2_kernel(const int* __restrict__ BO,
                                                    const int* __restrict__ packed,
                                                    int* __restrict__ R,
                                                    float* __restrict__ dinv,
                                                    int* __restrict__ eidx, int N) {
    __shared__ int cnt[BNODES];
    __shared__ int buf[2][BNODES];
    int b = blockIdx.x;
    int tid = threadIdx.x;
    int lo = BO[b], hi = BO[b + 1];
    cnt[tid] = 0;
    __syncthreads();
    // pass 1: per-node degree histogram in LDS
    for (int e = lo + tid; e < hi; e += 512)
        atomicAdd(&cnt[packed[e] >> 17], 1);
    __syncthreads();
    int deg = cnt[tid];
    // 512-wide Hillis-Steele inclusive scan -> exclusive offsets
    int cur = 0;
    buf[0][tid] = deg;
    __syncthreads();
    for (int off = 1; off < 512; off <<= 1) {
        int t = buf[cur][tid] + ((tid >= off) ? buf[cur][tid - off] : 0);
        cur ^= 1;
        buf[cur][tid] = t;
        __syncthreads();
    }
    int excl = lo + buf[cur][tid] - deg;          // global CSR offset for this node
    int n = (b << BSHIFT) + tid;
    if (n < N) {
        R[n] = excl;
        dinv[n] = rsqrtf((float)(deg + 1));       // +1 = self-loop
    }
    cnt[tid] = excl;                              // reuse as per-node cursor
    __syncthreads();
    // pass 2: counting scatter; writes stay inside [BO[b], BO[b+1]) — L2-local
    for (int e = lo + tid; e < hi; e += 512) {
        int p = packed[e];
        int pos = atomicAdd(&cnt[p >> 17], 1);
        eidx[pos] = p & SRC_MASK;
    }
}

// ---------------- GEMM1: g1 = (x @ W1) * dinv ----------------
// W is wave-uniform -> read from global with uniform indices (compiler emits s_load
// into SGPRs via scalar cache; v_fma takes one SGPR operand). No W tile in LDS.
// x staged in LDS: 16-float chunks, stride 17 (2-way banks = free), double-buffered,
// ONE barrier per chunk; global loads for chunk kc+1 issued before the barrier so
// the 256-FMA compute phase hides HBM latency. LDS = 34.8 KB -> 4 blocks/CU.

__global__ void __launch_bounds__(256) gemm1_kernel(const float* __restrict__ x,
                                                    const float* __restrict__ W1,
                                                    const float* __restrict__ dinv,
                                                    float* __restrict__ g1, int N) {
    __shared__ float xs[2][256 * 17];
    int tid = threadIdx.x;
    int rowbase = blockIdx.x * 256;
    int r0 = tid >> 2;           // 4 lanes per row
    int seg = tid & 3;           // 16B segment within the 16-float chunk
    float4 pv[4];

    // prefetch chunk 0
#pragma unroll
    for (int rep = 0; rep < 4; ++rep) {
        int gr = rowbase + r0 + rep * 64;
        pv[rep] = make_float4(0.f, 0.f, 0.f, 0.f);
        if (gr < N) pv[rep] = *(const float4*)(x + (size_t)gr * F_IN + seg * 4);
    }
#pragma unroll
    for (int rep = 0; rep < 4; ++rep) {
        float* dp = &xs[0][(r0 + rep * 64) * 17 + seg * 4];  // scalar stores: stride-17 rows
        dp[0] = pv[rep].x; dp[1] = pv[rep].y; dp[2] = pv[rep].z; dp[3] = pv[rep].w;
    }

    float acc[H_DIM];
#pragma unroll
    for (int k = 0; k < H_DIM; k++) acc[k] = 0.0f;

    for (int kc = 0; kc < F_IN / 16; ++kc) {
        if (kc + 1 < F_IN / 16) {   // issue next chunk's global loads (latency hidden under FMA)
#pragma unroll
            for (int rep = 0; rep < 4; ++rep) {
                int gr = rowbase + r0 + rep * 64;
                pv[rep] = make_float4(0.f, 0.f, 0.f, 0.f);
                if (gr < N)
                    pv[rep] = *(const float4*)(x + (size_t)gr * F_IN + (kc + 1) * 16 + seg * 4);
            }
        }
        __syncthreads();            // xs[kc&1] writes (prev iter) visible; prev reads of xs[(kc+1)&1] done
        const float* xr = &xs[kc & 1][tid * 17];
        const float4* Wk = (const float4*)(W1 + kc * 16 * H_DIM);  // uniform -> SGPR loads
#pragma unroll
        for (int j = 0; j < 16; ++j) {
            float s = xr[j];
#pragma unroll
            for (int p = 0; p < 4; ++p) {
                float4 wv = Wk[j * 4 + p];
                acc[4 * p + 0] += s * wv.x;
                acc[4 * p + 1] += s * wv.y;
                acc[4 * p + 2] += s * wv.z;
                acc[4 * p + 3] += s * wv.w;
            }
        }
        if (kc + 1 < F_IN / 16) {   // write-late into the other buffer (no barrier needed here)
#pragma unroll
            for (int rep = 0; rep < 4; ++rep) {
                float* dp = &xs[(kc + 1) & 1][(r0 + rep * 64) * 17 + seg * 4];
                dp[0] = pv[rep].x; dp[1] = pv[rep].y; dp[2] = pv[rep].z; dp[3] = pv[rep].w;
            }
        }
    }

    int row = rowbase + tid;
    if (row < N) {
        float di = dinv[row];
        float4* o = (float4*)(g1 + (size_t)row * H_DIM);
#pragma unroll
        for (int p = 0; p < 4; p++)
            o[p] = make_float4(acc[4 * p] * di, acc[4 * p + 1] * di,
                               acc[4 * p + 2] * di, acc[4 * p + 3] * di);
    }
}

// ---------------- node-parallel CSR aggregation, register accumulate, unroll 8 ----------------

// layer 1: g2 = dinv * relu(dinv*(sum + self) + b1)
__global__ void __launch_bounds__(256) agg1_kernel(const int* __restrict__ R,
                                                   const int* __restrict__ eidx,
                                                   const float* __restrict__ g1,
                                                   const float* __restrict__ dinv,
                                                   const float* __restrict__ b1,
                                                   float* __restrict__ g2, int N) {
    int t = blockIdx.x * 256 + threadIdx.x;
    int n = t >> 4;
    if (n >= N) return;
    int k = t & 15;
    int lo = R[n], hi = R[n + 1];
    float sum = g1[t];  // self-loop (g1 = dinv*h1)
    int e = lo;
    for (; e + 8 <= hi; e += 8) {
        int s[8];
        float v[8];
#pragma unroll
        for (int u = 0; u < 8; u++) s[u] = eidx[e + u];
#pragma unroll
        for (int u = 0; u < 8; u++) v[u] = g1[s[u] * H_DIM + k];
#pragma unroll
        for (int u = 0; u < 8; u++) sum += v[u];
    }
    for (; e < hi; ++e) sum += g1[eidx[e] * H_DIM + k];
    float di = dinv[n];
    g2[t] = di * fmaxf(di * sum + b1[k], 0.0f);
}

// layer 2: s2 = sum + self (dinv, W2, b2 applied in final)
__global__ void __launch_bounds__(256) agg2_kernel(const int* __restrict__ R,
                                                   const int* __restrict__ eidx,
                                                   const float* __restrict__ g2,
                                                   float* __restrict__ s2, int N) {
    int t = blockIdx.x * 256 + threadIdx.x;
    int n = t >> 4;
    if (n >= N) return;
    int k = t & 15;
    int lo = R[n], hi = R[n + 1];
    float sum = g2[t];
    int e = lo;
    for (; e + 8 <= hi; e += 8) {
        int s[8];
        float v[8];
#pragma unroll
        for (int u = 0; u < 8; u++) s[u] = eidx[e + u];
#pragma unroll
        for (int u = 0; u < 8; u++) v[u] = g2[s[u] * H_DIM + k];
#pragma unroll
        for (int u = 0; u < 8; u++) sum += v[u];
    }
    for (; e < hi; ++e) sum += g2[eidx[e] * H_DIM + k];
    s2[t] = sum;
}

// ---------------- final: v = dinv*s2; logits = v@W2 + b2; log_softmax; coalesced writes ----------------

__global__ void __launch_bounds__(256) final_kernel(const float* __restrict__ s2,
                                                    const float* __restrict__ dinv,
                                                    const float* __restrict__ W2,
                                                    const float* __restrict__ b2,
                                                    float* __restrict__ out, int N) {
    __shared__ float w2s[H_DIM * C_DIM];
    __shared__ float b2s[C_DIM];
    __shared__ float stage[256 * 41];
    for (int i = threadIdx.x; i < H_DIM * C_DIM; i += 256) w2s[i] = W2[i];
    if (threadIdx.x < C_DIM) b2s[threadIdx.x] = b2[threadIdx.x];
    __syncthreads();
    int n = blockIdx.x * 256 + threadIdx.x;
    int cn = n < N ? n : 0;
    float di = dinv[cn];
    float v[H_DIM];
    const float4* sv = (const float4*)(s2 + (size_t)cn * H_DIM);
#pragma unroll
    for (int p = 0; p < 4; p++) {
        float4 t = sv[p];
        v[4 * p] = di * t.x; v[4 * p + 1] = di * t.y;
        v[4 * p + 2] = di * t.z; v[4 * p + 3] = di * t.w;
    }
    float lg[C_DIM];
    float m = -1e30f;
    for (int c = 0; c < C_DIM; c++) {
        float a = b2s[c];
#pragma unroll
        for (int k = 0; k < H_DIM; k++) a += v[k] * w2s[k * C_DIM + c];
        lg[c] = a;
        m = fmaxf(m, a);
    }
    float ssum = 0.0f;
    for (int c = 0; c < C_DIM; c++) ssum += __expf(lg[c] - m);
    float lse = m + __logf(ssum);

    size_t base = (size_t)blockIdx.x * 256 * C_DIM;
    size_t lim = (size_t)N * C_DIM;
    for (int c = 0; c < C_DIM; c++) stage[threadIdx.x * 41 + c] = lg[c] - lse;
    __syncthreads();
    for (int i = threadIdx.x; i < 256 * C_DIM; i += 256) {
        int nn = i / C_DIM, c = i - nn * C_DIM;
        size_t g = base + i;
        if (g < lim) out[g] = stage[nn * 41 + c];
    }
    __syncthreads();
    for (int c = 0; c < C_DIM; c++) stage[threadIdx.x * 41 + c] = lg[c];
    __syncthreads();
    for (int i = threadIdx.x; i < 256 * C_DIM; i += 256) {
        int nn = i / C_DIM, c = i - nn * C_DIM;
        size_t g = base + i;
        if (g < lim) out[lim + g] = stage[nn * 41 + c];
    }
}

// ---------------- launch ----------------

extern "C" void kernel_launch(void* const* d_in, const int* in_sizes, int n_in,
                              void* d_out, int out_size, void* d_ws, size_t ws_size,
                              hipStream_t stream) {
    const float* x  = (const float*)d_in[0];
    const int* ei   = (const int*)d_in[1];
    const float* W1 = (const float*)d_in[2];
    const float* b1 = (const float*)d_in[3];
    const float* W2 = (const float*)d_in[4];
    const float* b2 = (const float*)d_in[5];
    float* out = (float*)d_out;

    const int N = N_NODES;
    const int E = in_sizes[1] / 2;
    const int* src = ei;
    const int* dst = ei + E;

    // ws layout (ints): R[N+16] | BC[512] | BO[256] | cursor[256] | dinv[N+16] | eidx[E] |
    //                   union{ packed[E]  |  g1[16N] + g2[16N] }     (~26.4 MB total)
    int* R      = (int*)d_ws;                 // CSR node offsets (R[N] = E)
    int* BC     = R + 100016;                 // bucket counts
    int* BO     = BC + 512;                   // bucket offsets (exclusive scan)
    int* cursor = BO + 256;
    float* dinv = (float*)(cursor + 256);
    int* eidx   = (int*)(dinv + 100016);
    int* packed = eidx + E;                   // dead after sort2_kernel
    float* g1   = (float*)packed;             // reuses packed region
    float* g2   = g1 + 16 * N;
    float* s2   = g1;                         // g1 dead after agg1

    const int NB = (N + 255) / 256;  // 391
    const int NCH = (E + CHUNK - 1) / CHUNK;

    hipMemsetAsync(BC, 0, NBUCK * sizeof(int), stream);
    bhist_kernel<<<NCH, 256, 0, stream>>>(dst, BC, E);
    bscan_kernel<<<1, 256, 0, stream>>>(BC, BO, cursor, R, E, N);
    partition_kernel<<<NCH, 256, 0, stream>>>(src, dst, cursor, packed, E);
    sort2_kernel<<<NBUCK, 512, 0, stream>>>(BO, packed, R, dinv, eidx, N);

    gemm1_kernel<<<NB, 256, 0, stream>>>(x, W1, dinv, g1, N);
    agg1_kernel<<<(N * 16 + 255) / 256, 256, 0, stream>>>(R, eidx, g1, dinv, b1, g2, N);
    agg2_kernel<<<(N * 16 + 255) / 256, 256, 0, stream>>>(R, eidx, g2, s2, N);
    final_kernel<<<NB, 256, 0, stream>>>(s2, dinv, W2, b2, out, N);
}

// Round 4
// 534.932 us; speedup vs baseline: 1.2111x; 1.0149x over previous
//
#include <hip/hip_runtime.h>
#include <hip/hip_bf16.h>
#include <math.h>

#define N_NODES 100000
#define F_IN 512
#define H_DIM 16
#define C_DIM 40

#define BSHIFT 9                       // 512 nodes per bucket
#define BNODES 512
#define NBUCK 196                      // ceil(100000 / 512)
#define CHUNK 8192                     // edges per partition block
#define SRC_MASK 0x1FFFF               // 17 bits (N < 131072)

// ---------------- bucket histogram (196 bins) ----------------

__global__ void __launch_bounds__(256) bhist_kernel(const int* __restrict__ dst,
                                                    int* __restrict__ BC, int E) {
    __shared__ int cnt[NBUCK];
    int start = blockIdx.x * CHUNK;
    int end = start + CHUNK < E ? start + CHUNK : E;
    for (int i = threadIdx.x; i < NBUCK; i += 256) cnt[i] = 0;
    __syncthreads();
    for (int i = start + threadIdx.x; i < end; i += 256)
        atomicAdd(&cnt[dst[i] >> BSHIFT], 1);
    __syncthreads();
    for (int i = threadIdx.x; i < NBUCK; i += 256) {
        int c = cnt[i];
        if (c) atomicAdd(&BC[i], c);
    }
}

// ---------------- scan of 196 bucket counts -> BO / cursor; R[N]=E ----------------

__global__ void __launch_bounds__(256) bscan_kernel(const int* __restrict__ BC,
                                                    int* __restrict__ BO,
                                                    int* __restrict__ cursor,
                                                    int* __restrict__ R, int E, int N) {
    __shared__ int buf[2][256];
    int tid = threadIdx.x;
    int v = (tid < NBUCK) ? BC[tid] : 0;
    int cur = 0;
    buf[0][tid] = v;
    __syncthreads();
    for (int off = 1; off < 256; off <<= 1) {
        int t = buf[cur][tid] + ((tid >= off) ? buf[cur][tid - off] : 0);
        cur ^= 1;
        buf[cur][tid] = t;
        __syncthreads();
    }
    int excl = buf[cur][tid] - v;                 // exclusive prefix
    if (tid <= NBUCK) {                           // tid==NBUCK -> total == E
        BO[tid] = excl;
        if (tid < NBUCK) cursor[tid] = excl;
    }
    if (tid == 0) R[N] = E;
}

// ---------------- radix partition by dst bucket; packed = (local_dst<<17)|src ----------------

__global__ void __launch_bounds__(256) partition_kernel(const int* __restrict__ src,
                                                        const int* __restrict__ dst,
                                                        int* __restrict__ cursor,
                                                        int* __restrict__ packed, int E) {
    __shared__ int cnt[NBUCK];
    __shared__ int base[NBUCK];
    int start = blockIdx.x * CHUNK;
    int end = start + CHUNK < E ? start + CHUNK : E;
    for (int i = threadIdx.x; i < NBUCK; i += 256) cnt[i] = 0;
    __syncthreads();
    for (int i = start + threadIdx.x; i < end; i += 256)
        atomicAdd(&cnt[dst[i] >> BSHIFT], 1);
    __syncthreads();
    for (int i = threadIdx.x; i < NBUCK; i += 256) {
        int c = cnt[i];
        base[i] = c ? atomicAdd(&cursor[i], c) : 0;
        cnt[i] = 0;  // reuse as local position
    }
    __syncthreads();
    for (int i = start + threadIdx.x; i < end; i += 256) {
        int d = dst[i];
        int b = d >> BSHIFT;
        int p = base[b] + atomicAdd(&cnt[b], 1);
        packed[p] = ((d & (BNODES - 1)) << 17) | src[i];
    }
}

// ---------------- per-bucket: degree hist + scan -> R/dinv, then counting scatter -> eidx ----------------

__global__ void __launch_bounds__(512) sort2_kernel(const int* __restrict__ BO,
                                                    const int* __restrict__ packed,
                                                    int* __restrict__ R,
                                                    float* __restrict__ dinv,
                                                    int* __restrict__ eidx, int N) {
    __shared__ int cnt[BNODES];
    __shared__ int buf[2][BNODES];
    int b = blockIdx.x;
    int tid = threadIdx.x;
    int lo = BO[b], hi = BO[b + 1];
    cnt[tid] = 0;
    __syncthreads();
    // pass 1: per-node degree histogram in LDS
    for (int e = lo + tid; e < hi; e += 512)
        atomicAdd(&cnt[packed[e] >> 17], 1);
    __syncthreads();
    int deg = cnt[tid];
    // 512-wide Hillis-Steele inclusive scan -> exclusive offsets
    int cur = 0;
    buf[0][tid] = deg;
    __syncthreads();
    for (int off = 1; off < 512; off <<= 1) {
        int t = buf[cur][tid] + ((tid >= off) ? buf[cur][tid - off] : 0);
        cur ^= 1;
        buf[cur][tid] = t;
        __syncthreads();
    }
    int excl = lo + buf[cur][tid] - deg;          // global CSR offset for this node
    int n = (b << BSHIFT) + tid;
    if (n < N) {
        R[n] = excl;
        dinv[n] = rsqrtf((float)(deg + 1));       // +1 = self-loop
    }
    cnt[tid] = excl;                              // reuse as per-node cursor
    __syncthreads();
    // pass 2: counting scatter; writes stay inside [BO[b], BO[b+1]) — L2-local
    for (int e = lo + tid; e < hi; e += 512) {
        int p = packed[e];
        int pos = atomicAdd(&cnt[p >> 17], 1);
        eidx[pos] = p & SRC_MASK;
    }
}

// ---------------- GEMM1: g1 = (x @ W1) * dinv ----------------
// No LDS, no barriers. 64-thread wave-blocks (1563 blocks). Each lane streams its own
// row: per 16-float K-chunk one 64B line via 4 back-to-back float4 loads (MSHR-merged
// -> 1 fetch/line). Double-buffered in registers; next chunk's loads issued before the
// 256-FMA compute block so HBM latency hides under FMA. W is wave-uniform -> s_load
// through scalar cache (no VMEM, no LDS). ~60 VGPR -> 8 waves/SIMD.

#define G1_ISSUE(BUF, KC)                                            \
    {                                                                \
        _Pragma("unroll")                                            \
        for (int p = 0; p < 4; ++p) BUF[p] = xr[(KC) * 4 + p];       \
    }

#define G1_COMPUTE(BUF, KC)                                          \
    {                                                                \
        const float4* Wk = (const float4*)(W1 + (KC) * 16 * H_DIM);  \
        const float* xf = (const float*)BUF;                         \
        _Pragma("unroll")                                            \
        for (int j = 0; j < 16; ++j) {                               \
            float s = xf[j];                                         \
            _Pragma("unroll")                                        \
            for (int p = 0; p < 4; ++p) {                            \
                float4 wv = Wk[j * 4 + p];                           \
                acc[4 * p + 0] += s * wv.x;                          \
                acc[4 * p + 1] += s * wv.y;                          \
                acc[4 * p + 2] += s * wv.z;                          \
                acc[4 * p + 3] += s * wv.w;                          \
            }                                                        \
        }                                                            \
    }

__global__ void __launch_bounds__(64) gemm1_kernel(const float* __restrict__ x,
                                                   const float* __restrict__ W1,
                                                   const float* __restrict__ dinv,
                                                   float* __restrict__ g1, int N) {
    int row = blockIdx.x * 64 + threadIdx.x;
    int cr = row < N ? row : N - 1;               // tail lanes re-read row N-1 (discarded)
    const float4* xr = (const float4*)(x + (size_t)cr * F_IN);

    float4 bufA[4], bufB[4];
    float acc[H_DIM];
#pragma unroll
    for (int k = 0; k < H_DIM; k++) acc[k] = 0.0f;

    G1_ISSUE(bufA, 0);
#pragma unroll
    for (int kc = 0; kc < F_IN / 16; kc += 2) {   // 32 chunks, 2 per iteration (A/B ping-pong)
        G1_ISSUE(bufB, kc + 1);                   // in flight during A's compute
        G1_COMPUTE(bufA, kc);
        if (kc + 2 < F_IN / 16) G1_ISSUE(bufA, kc + 2);  // in flight during B's compute
        G1_COMPUTE(bufB, kc + 1);
    }

    if (row < N) {
        float di = dinv[row];
        float4* o = (float4*)(g1 + (size_t)row * H_DIM);
#pragma unroll
        for (int p = 0; p < 4; p++)
            o[p] = make_float4(acc[4 * p] * di, acc[4 * p + 1] * di,
                               acc[4 * p + 2] * di, acc[4 * p + 3] * di);
    }
}

// ---------------- node-parallel CSR aggregation, register accumulate, unroll 8 ----------------

// layer 1: g2 = dinv * relu(dinv*(sum + self) + b1)
__global__ void __launch_bounds__(256) agg1_kernel(const int* __restrict__ R,
                                                   const int* __restrict__ eidx,
                                                   const float* __restrict__ g1,
                                                   const float* __restrict__ dinv,
                                                   const float* __restrict__ b1,
                                                   float* __restrict__ g2, int N) {
    int t = blockIdx.x * 256 + threadIdx.x;
    int n = t >> 4;
    if (n >= N) return;
    int k = t & 15;
    int lo = R[n], hi = R[n + 1];
    float sum = g1[t];  // self-loop (g1 = dinv*h1)
    int e = lo;
    for (; e + 8 <= hi; e += 8) {
        int s[8];
        float v[8];
#pragma unroll
        for (int u = 0; u < 8; u++) s[u] = eidx[e + u];
#pragma unroll
        for (int u = 0; u < 8; u++) v[u] = g1[s[u] * H_DIM + k];
#pragma unroll
        for (int u = 0; u < 8; u++) sum += v[u];
    }
    for (; e < hi; ++e) sum += g1[eidx[e] * H_DIM + k];
    float di = dinv[n];
    g2[t] = di * fmaxf(di * sum + b1[k], 0.0f);
}

// layer 2: s2 = sum + self (dinv, W2, b2 applied in final)
__global__ void __launch_bounds__(256) agg2_kernel(const int* __restrict__ R,
                                                   const int* __restrict__ eidx,
                                                   const float* __restrict__ g2,
                                                   float* __restrict__ s2, int N) {
    int t = blockIdx.x * 256 + threadIdx.x;
    int n = t >> 4;
    if (n >= N) return;
    int k = t & 15;
    int lo = R[n], hi = R[n + 1];
    float sum = g2[t];
    int e = lo;
    for (; e + 8 <= hi; e += 8) {
        int s[8];
        float v[8];
#pragma unroll
        for (int u = 0; u < 8; u++) s[u] = eidx[e + u];
#pragma unroll
        for (int u = 0; u < 8; u++) v[u] = g2[s[u] * H_DIM + k];
#pragma unroll
        for (int u = 0; u < 8; u++) sum += v[u];
    }
    for (; e < hi; ++e) sum += g2[eidx[e] * H_DIM + k];
    s2[t] = sum;
}

// ---------------- final: v = dinv*s2; logits = v@W2 + b2; log_softmax; coalesced writes ----------------

__global__ void __launch_bounds__(256) final_kernel(const float* __restrict__ s2,
                                                    const float* __restrict__ dinv,
                                                    const float* __restrict__ W2,
                                                    const float* __restrict__ b2,
                                                    float* __restrict__ out, int N) {
    __shared__ float w2s[H_DIM * C_DIM];
    __shared__ float b2s[C_DIM];
    __shared__ float stage[256 * 41];
    for (int i = threadIdx.x; i < H_DIM * C_DIM; i += 256) w2s[i] = W2[i];
    if (threadIdx.x < C_DIM) b2s[threadIdx.x] = b2[threadIdx.x];
    __syncthreads();
    int n = blockIdx.x * 256 + threadIdx.x;
    int cn = n < N ? n : 0;
    float di = dinv[cn];
    float v[H_DIM];
    const float4* sv = (const float4*)(s2 + (size_t)cn * H_DIM);
#pragma unroll
    for (int p = 0; p < 4; p++) {
        float4 t = sv[p];
        v[4 * p] = di * t.x; v[4 * p + 1] = di * t.y;
        v[4 * p + 2] = di * t.z; v[4 * p + 3] = di * t.w;
    }
    float lg[C_DIM];
    float m = -1e30f;
    for (int c = 0; c < C_DIM; c++) {
        float a = b2s[c];
#pragma unroll
        for (int k = 0; k < H_DIM; k++) a += v[k] * w2s[k * C_DIM + c];
        lg[c] = a;
        m = fmaxf(m, a);
    }
    float ssum = 0.0f;
    for (int c = 0; c < C_DIM; c++) ssum += __expf(lg[c] - m);
    float lse = m + __logf(ssum);

    size_t base = (size_t)blockIdx.x * 256 * C_DIM;
    size_t lim = (size_t)N * C_DIM;
    for (int c = 0; c < C_DIM; c++) stage[threadIdx.x * 41 + c] = lg[c] - lse;
    __syncthreads();
    for (int i = threadIdx.x; i < 256 * C_DIM; i += 256) {
        int nn = i / C_DIM, c = i - nn * C_DIM;
        size_t g = base + i;
        if (g < lim) out[g] = stage[nn * 41 + c];
    }
    __syncthreads();
    for (int c = 0; c < C_DIM; c++) stage[threadIdx.x * 41 + c] = lg[c];
    __syncthreads();
    for (int i = threadIdx.x; i < 256 * C_DIM; i += 256) {
        int nn = i / C_DIM, c = i - nn * C_DIM;
        size_t g = base + i;
        if (g < lim) out[lim + g] = stage[nn * 41 + c];
    }
}

// ---------------- launch ----------------

extern "C" void kernel_launch(void* const* d_in, const int* in_sizes, int n_in,
                              void* d_out, int out_size, void* d_ws, size_t ws_size,
                              hipStream_t stream) {
    const float* x  = (const float*)d_in[0];
    const int* ei   = (const int*)d_in[1];
    const float* W1 = (const float*)d_in[2];
    const float* b1 = (const float*)d_in[3];
    const float* W2 = (const float*)d_in[4];
    const float* b2 = (const float*)d_in[5];
    float* out = (float*)d_out;

    const int N = N_NODES;
    const int E = in_sizes[1] / 2;
    const int* src = ei;
    const int* dst = ei + E;

    // ws layout (ints): R[N+16] | BC[512] | BO[256] | cursor[256] | dinv[N+16] | eidx[E] |
    //                   union{ packed[E]  |  g1[16N] + g2[16N] }     (~26.4 MB total)
    int* R      = (int*)d_ws;                 // CSR node offsets (R[N] = E)
    int* BC     = R + 100016;                 // bucket counts
    int* BO     = BC + 512;                   // bucket offsets (exclusive scan)
    int* cursor = BO + 256;
    float* dinv = (float*)(cursor + 256);
    int* eidx   = (int*)(dinv + 100016);
    int* packed = eidx + E;                   // dead after sort2_kernel
    float* g1   = (float*)packed;             // reuses packed region
    float* g2   = g1 + 16 * N;
    float* s2   = g1;                         // g1 dead after agg1

    const int NB = (N + 255) / 256;  // 391
    const int NCH = (E + CHUNK - 1) / CHUNK;

    hipMemsetAsync(BC, 0, NBUCK * sizeof(int), stream);
    bhist_kernel<<<NCH, 256, 0, stream>>>(dst, BC, E);
    bscan_kernel<<<1, 256, 0, stream>>>(BC, BO, cursor, R, E, N);
    partition_kernel<<<NCH, 256, 0, stream>>>(src, dst, cursor, packed, E);
    sort2_kernel<<<NBUCK, 512, 0, stream>>>(BO, packed, R, dinv, eidx, N);

    gemm1_kernel<<<(N + 63) / 64, 64, 0, stream>>>(x, W1, dinv, g1, N);
    agg1_kernel<<<(N * 16 + 255) / 256, 256, 0, stream>>>(R, eidx, g1, dinv, b1, g2, N);
    agg2_kernel<<<(N * 16 + 255) / 256, 256, 0, stream>>>(R, eidx, g2, s2, N);
    final_kernel<<<NB, 256, 0, stream>>>(s2, dinv, W2, b2, out, N);
}

// Round 5
// 531.410 us; speedup vs baseline: 1.2191x; 1.0066x over previous
//
#include <hip/hip_runtime.h>
#include <hip/hip_bf16.h>
#include <math.h>

#define N_NODES 100000
#define F_IN 512
#define H_DIM 16
#define C_DIM 40

#define BSHIFT 9                       // 512 nodes per bucket
#define BNODES 512
#define NBUCK 196                      // ceil(100000 / 512)
#define CHUNK 8192                     // edges per partition block
#define SRC_MASK 0x1FFFF               // 17 bits (N < 131072)

#define KSPLIT 4
#define KSEG (F_IN / KSPLIT)           // 128 floats = 8 chunks of 16

// ---------------- bucket histogram (196 bins) ----------------

__global__ void __launch_bounds__(256) bhist_kernel(const int* __restrict__ dst,
                                                    int* __restrict__ BC, int E) {
    __shared__ int cnt[NBUCK];
    int start = blockIdx.x * CHUNK;
    int end = start + CHUNK < E ? start + CHUNK : E;
    for (int i = threadIdx.x; i < NBUCK; i += 256) cnt[i] = 0;
    __syncthreads();
    for (int i = start + threadIdx.x; i < end; i += 256)
        atomicAdd(&cnt[dst[i] >> BSHIFT], 1);
    __syncthreads();
    for (int i = threadIdx.x; i < NBUCK; i += 256) {
        int c = cnt[i];
        if (c) atomicAdd(&BC[i], c);
    }
}

// ---------------- scan of 196 bucket counts -> BO / cursor; R[N]=E ----------------

__global__ void __launch_bounds__(256) bscan_kernel(const int* __restrict__ BC,
                                                    int* __restrict__ BO,
                                                    int* __restrict__ cursor,
                                                    int* __restrict__ R, int E, int N) {
    __shared__ int buf[2][256];
    int tid = threadIdx.x;
    int v = (tid < NBUCK) ? BC[tid] : 0;
    int cur = 0;
    buf[0][tid] = v;
    __syncthreads();
    for (int off = 1; off < 256; off <<= 1) {
        int t = buf[cur][tid] + ((tid >= off) ? buf[cur][tid - off] : 0);
        cur ^= 1;
        buf[cur][tid] = t;
        __syncthreads();
    }
    int excl = buf[cur][tid] - v;                 // exclusive prefix
    if (tid <= NBUCK) {                           // tid==NBUCK -> total == E
        BO[tid] = excl;
        if (tid < NBUCK) cursor[tid] = excl;
    }
    if (tid == 0) R[N] = E;
}

// ---------------- radix partition by dst bucket; packed = (local_dst<<17)|src ----------------

__global__ void __launch_bounds__(256) partition_kernel(const int* __restrict__ src,
                                                        const int* __restrict__ dst,
                                                        int* __restrict__ cursor,
                                                        int* __restrict__ packed, int E) {
    __shared__ int cnt[NBUCK];
    __shared__ int base[NBUCK];
    int start = blockIdx.x * CHUNK;
    int end = start + CHUNK < E ? start + CHUNK : E;
    for (int i = threadIdx.x; i < NBUCK; i += 256) cnt[i] = 0;
    __syncthreads();
    for (int i = start + threadIdx.x; i < end; i += 256)
        atomicAdd(&cnt[dst[i] >> BSHIFT], 1);
    __syncthreads();
    for (int i = threadIdx.x; i < NBUCK; i += 256) {
        int c = cnt[i];
        base[i] = c ? atomicAdd(&cursor[i], c) : 0;
        cnt[i] = 0;  // reuse as local position
    }
    __syncthreads();
    for (int i = start + threadIdx.x; i < end; i += 256) {
        int d = dst[i];
        int b = d >> BSHIFT;
        int p = base[b] + atomicAdd(&cnt[b], 1);
        packed[p] = ((d & (BNODES - 1)) << 17) | src[i];
    }
}

// ---------------- per-bucket: degree hist + scan -> R/dinv, then counting scatter -> eidx ----------------

__global__ void __launch_bounds__(512) sort2_kernel(const int* __restrict__ BO,
                                                    const int* __restrict__ packed,
                                                    int* __restrict__ R,
                                                    float* __restrict__ dinv,
                                                    int* __restrict__ eidx, int N) {
    __shared__ int cnt[BNODES];
    __shared__ int buf[2][BNODES];
    int b = blockIdx.x;
    int tid = threadIdx.x;
    int lo = BO[b], hi = BO[b + 1];
    cnt[tid] = 0;
    __syncthreads();
    // pass 1: per-node degree histogram in LDS
    for (int e = lo + tid; e < hi; e += 512)
        atomicAdd(&cnt[packed[e] >> 17], 1);
    __syncthreads();
    int deg = cnt[tid];
    // 512-wide Hillis-Steele inclusive scan -> exclusive offsets
    int cur = 0;
    buf[0][tid] = deg;
    __syncthreads();
    for (int off = 1; off < 512; off <<= 1) {
        int t = buf[cur][tid] + ((tid >= off) ? buf[cur][tid - off] : 0);
        cur ^= 1;
        buf[cur][tid] = t;
        __syncthreads();
    }
    int excl = lo + buf[cur][tid] - deg;          // global CSR offset for this node
    int n = (b << BSHIFT) + tid;
    if (n < N) {
        R[n] = excl;
        dinv[n] = rsqrtf((float)(deg + 1));       // +1 = self-loop
    }
    cnt[tid] = excl;                              // reuse as per-node cursor
    __syncthreads();
    // pass 2: counting scatter; writes stay inside [BO[b], BO[b+1]) — L2-local
    for (int e = lo + tid; e < hi; e += 512) {
        int p = packed[e];
        int pos = atomicAdd(&cnt[p >> 17], 1);
        eidx[pos] = p & SRC_MASK;
    }
}

// ---------------- GEMM1 (split-K): part[ks] = x[:, ks*128:(ks+1)*128] @ W1[seg] ----------------
// The old full-K kernel had only 1563 waves chip-wide (1.5/SIMD) -> every load latency
// exposed (VALUBusy 9%). Split K by 4 -> 6252 waves (4/SIMD dispatch), same total x
// traffic (each K-segment read exactly once). Register ping-pong, no LDS, no barriers.

#define G1_ISSUE(BUF, KC)                                            \
    {                                                                \
        _Pragma("unroll")                                            \
        for (int p = 0; p < 4; ++p) BUF[p] = xr[(KC) * 4 + p];       \
    }

#define G1_COMPUTE(BUF, KC)                                          \
    {                                                                \
        const float4* Wk = (const float4*)(Wb + (KC) * 16 * H_DIM);  \
        const float* xf = (const float*)BUF;                         \
        _Pragma("unroll")                                            \
        for (int j = 0; j < 16; ++j) {                               \
            float s = xf[j];                                         \
            _Pragma("unroll")                                        \
            for (int p = 0; p < 4; ++p) {                            \
                float4 wv = Wk[j * 4 + p];                           \
                acc[4 * p + 0] += s * wv.x;                          \
                acc[4 * p + 1] += s * wv.y;                          \
                acc[4 * p + 2] += s * wv.z;                          \
                acc[4 * p + 3] += s * wv.w;                          \
            }                                                        \
        }                                                            \
    }

__global__ void __launch_bounds__(64) gemm1p_kernel(const float* __restrict__ x,
                                                    const float* __restrict__ W1,
                                                    float* __restrict__ part, int N) {
    int bid = blockIdx.x;
    int ks = bid & (KSPLIT - 1);                  // consecutive blocks: same rows, diff K-seg
    int rb = bid >> 2;
    int row = rb * 64 + threadIdx.x;
    int cr = row < N ? row : N - 1;               // tail lanes re-read row N-1 (discarded)
    const float4* xr = (const float4*)(x + (size_t)cr * F_IN + ks * KSEG);
    const float* Wb = W1 + ks * KSEG * H_DIM;

    float4 bufA[4], bufB[4];
    float acc[H_DIM];
#pragma unroll
    for (int k = 0; k < H_DIM; k++) acc[k] = 0.0f;

    G1_ISSUE(bufA, 0);
#pragma unroll
    for (int kc = 0; kc < KSEG / 16; kc += 2) {   // 8 chunks, 2 per iteration (A/B ping-pong)
        G1_ISSUE(bufB, kc + 1);
        G1_COMPUTE(bufA, kc);
        if (kc + 2 < KSEG / 16) G1_ISSUE(bufA, kc + 2);
        G1_COMPUTE(bufB, kc + 1);
    }

    if (row < N) {
        float4* o = (float4*)(part + (size_t)ks * N * H_DIM + (size_t)row * H_DIM);
#pragma unroll
        for (int p = 0; p < 4; p++)
            o[p] = make_float4(acc[4 * p], acc[4 * p + 1], acc[4 * p + 2], acc[4 * p + 3]);
    }
}

// ---------------- reduce 4 partial planes, apply dinv: g1 = dinv * sum_ks part[ks] ----------------

__global__ void __launch_bounds__(256) g1red_kernel(const float* __restrict__ part,
                                                    const float* __restrict__ dinv,
                                                    float* __restrict__ g1, int N) {
    int t = blockIdx.x * 256 + threadIdx.x;       // float4 index over N*16 floats
    int total = N * H_DIM / 4;                    // 400000
    if (t >= total) return;
    const float4* p = (const float4*)part;
    float4 a = p[t];
    float4 b = p[t + (size_t)total];
    float4 c = p[t + (size_t)2 * total];
    float4 d = p[t + (size_t)3 * total];
    float di = dinv[t >> 2];                      // 4 float4 per node
    ((float4*)g1)[t] = make_float4(di * (((a.x + b.x) + c.x) + d.x),
                                   di * (((a.y + b.y) + c.y) + d.y),
                                   di * (((a.z + b.z) + c.z) + d.z),
                                   di * (((a.w + b.w) + c.w) + d.w));
}

// ---------------- node-parallel CSR aggregation, register accumulate, unroll 8 ----------------

// layer 1: g2 = dinv * relu(dinv*(sum + self) + b1)
__global__ void __launch_bounds__(256) agg1_kernel(const int* __restrict__ R,
                                                   const int* __restrict__ eidx,
                                                   const float* __restrict__ g1,
                                                   const float* __restrict__ dinv,
                                                   const float* __restrict__ b1,
                                                   float* __restrict__ g2, int N) {
    int t = blockIdx.x * 256 + threadIdx.x;
    int n = t >> 4;
    if (n >= N) return;
    int k = t & 15;
    int lo = R[n], hi = R[n + 1];
    float sum = g1[t];  // self-loop (g1 = dinv*h1)
    int e = lo;
    for (; e + 8 <= hi; e += 8) {
        int s[8];
        float v[8];
#pragma unroll
        for (int u = 0; u < 8; u++) s[u] = eidx[e + u];
#pragma unroll
        for (int u = 0; u < 8; u++) v[u] = g1[s[u] * H_DIM + k];
#pragma unroll
        for (int u = 0; u < 8; u++) sum += v[u];
    }
    for (; e < hi; ++e) sum += g1[eidx[e] * H_DIM + k];
    float di = dinv[n];
    g2[t] = di * fmaxf(di * sum + b1[k], 0.0f);
}

// layer 2: s2 = sum + self (dinv, W2, b2 applied in final)
__global__ void __launch_bounds__(256) agg2_kernel(const int* __restrict__ R,
                                                   const int* __restrict__ eidx,
                                                   const float* __restrict__ g2,
                                                   float* __restrict__ s2, int N) {
    int t = blockIdx.x * 256 + threadIdx.x;
    int n = t >> 4;
    if (n >= N) return;
    int k = t & 15;
    int lo = R[n], hi = R[n + 1];
    float sum = g2[t];
    int e = lo;
    for (; e + 8 <= hi; e += 8) {
        int s[8];
        float v[8];
#pragma unroll
        for (int u = 0; u < 8; u++) s[u] = eidx[e + u];
#pragma unroll
        for (int u = 0; u < 8; u++) v[u] = g2[s[u] * H_DIM + k];
#pragma unroll
        for (int u = 0; u < 8; u++) sum += v[u];
    }
    for (; e < hi; ++e) sum += g2[eidx[e] * H_DIM + k];
    s2[t] = sum;
}

// ---------------- final: v = dinv*s2; logits = v@W2 + b2; log_softmax; coalesced writes ----------------

__global__ void __launch_bounds__(256) final_kernel(const float* __restrict__ s2,
                                                    const float* __restrict__ dinv,
                                                    const float* __restrict__ W2,
                                                    const float* __restrict__ b2,
                                                    float* __restrict__ out, int N) {
    __shared__ float w2s[H_DIM * C_DIM];
    __shared__ float b2s[C_DIM];
    __shared__ float stage[256 * 41];
    for (int i = threadIdx.x; i < H_DIM * C_DIM; i += 256) w2s[i] = W2[i];
    if (threadIdx.x < C_DIM) b2s[threadIdx.x] = b2[threadIdx.x];
    __syncthreads();
    int n = blockIdx.x * 256 + threadIdx.x;
    int cn = n < N ? n : 0;
    float di = dinv[cn];
    float v[H_DIM];
    const float4* sv = (const float4*)(s2 + (size_t)cn * H_DIM);
#pragma unroll
    for (int p = 0; p < 4; p++) {
        float4 t = sv[p];
        v[4 * p] = di * t.x; v[4 * p + 1] = di * t.y;
        v[4 * p + 2] = di * t.z; v[4 * p + 3] = di * t.w;
    }
    float lg[C_DIM];
    float m = -1e30f;
    for (int c = 0; c < C_DIM; c++) {
        float a = b2s[c];
#pragma unroll
        for (int k = 0; k < H_DIM; k++) a += v[k] * w2s[k * C_DIM + c];
        lg[c] = a;
        m = fmaxf(m, a);
    }
    float ssum = 0.0f;
    for (int c = 0; c < C_DIM; c++) ssum += __expf(lg[c] - m);
    float lse = m + __logf(ssum);

    size_t base = (size_t)blockIdx.x * 256 * C_DIM;
    size_t lim = (size_t)N * C_DIM;
    for (int c = 0; c < C_DIM; c++) stage[threadIdx.x * 41 + c] = lg[c] - lse;
    __syncthreads();
    for (int i = threadIdx.x; i < 256 * C_DIM; i += 256) {
        int nn = i / C_DIM, c = i - nn * C_DIM;
        size_t g = base + i;
        if (g < lim) out[g] = stage[nn * 41 + c];
    }
    __syncthreads();
    for (int c = 0; c < C_DIM; c++) stage[threadIdx.x * 41 + c] = lg[c];
    __syncthreads();
    for (int i = threadIdx.x; i < 256 * C_DIM; i += 256) {
        int nn = i / C_DIM, c = i - nn * C_DIM;
        size_t g = base + i;
        if (g < lim) out[lim + g] = stage[nn * 41 + c];
    }
}

// ---------------- launch ----------------

extern "C" void kernel_launch(void* const* d_in, const int* in_sizes, int n_in,
                              void* d_out, int out_size, void* d_ws, size_t ws_size,
                              hipStream_t stream) {
    const float* x  = (const float*)d_in[0];
    const int* ei   = (const int*)d_in[1];
    const float* W1 = (const float*)d_in[2];
    const float* b1 = (const float*)d_in[3];
    const float* W2 = (const float*)d_in[4];
    const float* b2 = (const float*)d_in[5];
    float* out = (float*)d_out;

    const int N = N_NODES;
    const int E = in_sizes[1] / 2;
    const int* src = ei;
    const int* dst = ei + E;

    // ws layout (ints): R[N+16] | BC[512] | BO[256] | cursor[256] | dinv[N+16] | eidx[E] |
    //                   union{ packed[E] | g1[16N] + g2[16N] } | part[4*16N]   (~52 MB)
    int* R      = (int*)d_ws;                 // CSR node offsets (R[N] = E)
    int* BC     = R + 100016;                 // bucket counts
    int* BO     = BC + 512;                   // bucket offsets (exclusive scan)
    int* cursor = BO + 256;
    float* dinv = (float*)(cursor + 256);
    int* eidx   = (int*)(dinv + 100016);
    int* packed = eidx + E;                   // dead after sort2_kernel
    float* g1   = (float*)packed;             // reuses packed region
    float* g2   = g1 + 16 * N;
    float* s2   = g1;                         // g1 dead after agg1
    float* part = g2 + 16 * N;                // 4 partial planes (split-K)

    const int NB = (N + 255) / 256;  // 391
    const int NCH = (E + CHUNK - 1) / CHUNK;
    const int NRB = (N + 63) / 64;   // 1563 row-blocks

    hipMemsetAsync(BC, 0, NBUCK * sizeof(int), stream);
    bhist_kernel<<<NCH, 256, 0, stream>>>(dst, BC, E);
    bscan_kernel<<<1, 256, 0, stream>>>(BC, BO, cursor, R, E, N);
    partition_kernel<<<NCH, 256, 0, stream>>>(src, dst, cursor, packed, E);
    sort2_kernel<<<NBUCK, 512, 0, stream>>>(BO, packed, R, dinv, eidx, N);

    gemm1p_kernel<<<NRB * KSPLIT, 64, 0, stream>>>(x, W1, part, N);
    g1red_kernel<<<(N * H_DIM / 4 + 255) / 256, 256, 0, stream>>>(part, dinv, g1, N);
    agg1_kernel<<<(N * 16 + 255) / 256, 256, 0, stream>>>(R, eidx, g1, dinv, b1, g2, N);
    agg2_kernel<<<(N * 16 + 255) / 256, 256, 0, stream>>>(R, eidx, g2, s2, N);
    final_kernel<<<NB, 256, 0, stream>>>(s2, dinv, W2, b2, out, N);
}

// Round 6
// 530.669 us; speedup vs baseline: 1.2208x; 1.0014x over previous
//
#include <hip/hip_runtime.h>
#include <hip/hip_bf16.h>
#include <math.h>

#define N_NODES 100000
#define F_IN 512
#define H_DIM 16
#define C_DIM 40

#define BSHIFT 9                       // 512 nodes per bucket
#define BNODES 512
#define NBUCK 196                      // ceil(100000 / 512)
#define CHUNK 8192                     // edges per partition block
#define SRC_MASK 0x1FFFF               // 17 bits (N < 131072)

#define KSPLIT 4
#define KSEG (F_IN / KSPLIT)           // 128 floats = 4 groups of 32

// ---------------- bucket histogram (196 bins) ----------------

__global__ void __launch_bounds__(256) bhist_kernel(const int* __restrict__ dst,
                                                    int* __restrict__ BC, int E) {
    __shared__ int cnt[NBUCK];
    int start = blockIdx.x * CHUNK;
    int end = start + CHUNK < E ? start + CHUNK : E;
    for (int i = threadIdx.x; i < NBUCK; i += 256) cnt[i] = 0;
    __syncthreads();
    for (int i = start + threadIdx.x; i < end; i += 256)
        atomicAdd(&cnt[dst[i] >> BSHIFT], 1);
    __syncthreads();
    for (int i = threadIdx.x; i < NBUCK; i += 256) {
        int c = cnt[i];
        if (c) atomicAdd(&BC[i], c);
    }
}

// ---------------- scan of 196 bucket counts -> BO / cursor; R[N]=E ----------------

__global__ void __launch_bounds__(256) bscan_kernel(const int* __restrict__ BC,
                                                    int* __restrict__ BO,
                                                    int* __restrict__ cursor,
                                                    int* __restrict__ R, int E, int N) {
    __shared__ int buf[2][256];
    int tid = threadIdx.x;
    int v = (tid < NBUCK) ? BC[tid] : 0;
    int cur = 0;
    buf[0][tid] = v;
    __syncthreads();
    for (int off = 1; off < 256; off <<= 1) {
        int t = buf[cur][tid] + ((tid >= off) ? buf[cur][tid - off] : 0);
        cur ^= 1;
        buf[cur][tid] = t;
        __syncthreads();
    }
    int excl = buf[cur][tid] - v;                 // exclusive prefix
    if (tid <= NBUCK) {                           // tid==NBUCK -> total == E
        BO[tid] = excl;
        if (tid < NBUCK) cursor[tid] = excl;
    }
    if (tid == 0) R[N] = E;
}

// ---------------- radix partition by dst bucket; packed = (local_dst<<17)|src ----------------

__global__ void __launch_bounds__(256) partition_kernel(const int* __restrict__ src,
                                                        const int* __restrict__ dst,
                                                        int* __restrict__ cursor,
                                                        int* __restrict__ packed, int E) {
    __shared__ int cnt[NBUCK];
    __shared__ int base[NBUCK];
    int start = blockIdx.x * CHUNK;
    int end = start + CHUNK < E ? start + CHUNK : E;
    for (int i = threadIdx.x; i < NBUCK; i += 256) cnt[i] = 0;
    __syncthreads();
    for (int i = start + threadIdx.x; i < end; i += 256)
        atomicAdd(&cnt[dst[i] >> BSHIFT], 1);
    __syncthreads();
    for (int i = threadIdx.x; i < NBUCK; i += 256) {
        int c = cnt[i];
        base[i] = c ? atomicAdd(&cursor[i], c) : 0;
        cnt[i] = 0;  // reuse as local position
    }
    __syncthreads();
    for (int i = start + threadIdx.x; i < end; i += 256) {
        int d = dst[i];
        int b = d >> BSHIFT;
        int p = base[b] + atomicAdd(&cnt[b], 1);
        packed[p] = ((d & (BNODES - 1)) << 17) | src[i];
    }
}

// ---------------- per-bucket: degree hist + scan -> R/dinv, then counting scatter -> eidx ----------------
// 1024 threads/bucket (was 512): halves the latency-exposed edge-loop iterations of the
// most grid-starved kernel (196 blocks, <1/CU). Scan stays 512-wide (tid<512 guarded).

__global__ void __launch_bounds__(1024) sort2_kernel(const int* __restrict__ BO,
                                                     const int* __restrict__ packed,
                                                     int* __restrict__ R,
                                                     float* __restrict__ dinv,
                                                     int* __restrict__ eidx, int N) {
    __shared__ int cnt[BNODES];
    __shared__ int buf[2][BNODES];
    int b = blockIdx.x;
    int tid = threadIdx.x;
    int lo = BO[b], hi = BO[b + 1];
    if (tid < BNODES) cnt[tid] = 0;
    __syncthreads();
    // pass 1: per-node degree histogram in LDS
    for (int e = lo + tid; e < hi; e += 1024)
        atomicAdd(&cnt[packed[e] >> 17], 1);
    __syncthreads();
    int deg = (tid < BNODES) ? cnt[tid] : 0;
    // 512-wide Hillis-Steele inclusive scan -> exclusive offsets (tid<512 active)
    int cur = 0;
    if (tid < BNODES) buf[0][tid] = deg;
    __syncthreads();
    for (int off = 1; off < BNODES; off <<= 1) {
        int t = 0;
        if (tid < BNODES) t = buf[cur][tid] + ((tid >= off) ? buf[cur][tid - off] : 0);
        cur ^= 1;
        if (tid < BNODES) buf[cur][tid] = t;
        __syncthreads();
    }
    if (tid < BNODES) {
        int excl = lo + buf[cur][tid] - deg;      // global CSR offset for this node
        int n = (b << BSHIFT) + tid;
        if (n < N) {
            R[n] = excl;
            dinv[n] = rsqrtf((float)(deg + 1));   // +1 = self-loop
        }
        cnt[tid] = excl;                          // reuse as per-node cursor
    }
    __syncthreads();
    // pass 2: counting scatter; writes stay inside [BO[b], BO[b+1]) — L2-local
    for (int e = lo + tid; e < hi; e += 1024) {
        int p = packed[e];
        int pos = atomicAdd(&cnt[p >> 17], 1);
        eidx[pos] = p & SRC_MASK;
    }
}

// ---------------- GEMM1 (split-K): part[ks] = x[:, ks*128:(ks+1)*128] @ W1[seg] ----------------
// 256-thread blocks (1564 WGs), 2 groups of 32 floats (8 float4) in flight per lane,
// W read wave-uniform from global (scalar cache). Per-thread summation order identical
// to previous round -> partials bit-identical.

#define G1_ISSUE(BUF, G)                                             \
    {                                                                \
        _Pragma("unroll")                                            \
        for (int p = 0; p < 8; ++p) BUF[p] = xr[(G) * 8 + p];        \
    }

#define G1_COMPUTE(BUF, G)                                           \
    {                                                                \
        const float* xf = (const float*)(BUF);                       \
        _Pragma("unroll")                                            \
        for (int j = 0; j < 32; ++j) {                               \
            float s = xf[j];                                         \
            const float4* Wj = (const float4*)(Wb + ((G) * 32 + j) * H_DIM); \
            _Pragma("unroll")                                        \
            for (int p = 0; p < 4; ++p) {                            \
                float4 wv = Wj[p];                                   \
                acc[4 * p + 0] += s * wv.x;                          \
                acc[4 * p + 1] += s * wv.y;                          \
                acc[4 * p + 2] += s * wv.z;                          \
                acc[4 * p + 3] += s * wv.w;                          \
            }                                                        \
        }                                                            \
    }

__global__ void __launch_bounds__(256) gemm1p_kernel(const float* __restrict__ x,
                                                     const float* __restrict__ W1,
                                                     float* __restrict__ part, int N) {
    int bid = blockIdx.x;
    int ks = bid & (KSPLIT - 1);                  // consecutive blocks: same rows, diff K-seg
    int rb = bid >> 2;
    int row = rb * 256 + threadIdx.x;
    int cr = row < N ? row : N - 1;               // tail lanes re-read row N-1 (discarded)
    const float4* xr = (const float4*)(x + (size_t)cr * F_IN + ks * KSEG);
    const float* Wb = W1 + ks * KSEG * H_DIM;

    float4 bufA[8], bufB[8];
    float acc[H_DIM];
#pragma unroll
    for (int k = 0; k < H_DIM; k++) acc[k] = 0.0f;

    G1_ISSUE(bufA, 0);
    G1_ISSUE(bufB, 1);            // 2 groups (256 B/lane) in flight
    G1_COMPUTE(bufA, 0);
    G1_ISSUE(bufA, 2);
    G1_COMPUTE(bufB, 1);
    G1_ISSUE(bufB, 3);
    G1_COMPUTE(bufA, 2);
    G1_COMPUTE(bufB, 3);

    if (row < N) {
        float4* o = (float4*)(part + (size_t)ks * N * H_DIM + (size_t)row * H_DIM);
#pragma unroll
        for (int p = 0; p < 4; p++)
            o[p] = make_float4(acc[4 * p], acc[4 * p + 1], acc[4 * p + 2], acc[4 * p + 3]);
    }
}

// ---------------- reduce 4 partial planes, apply dinv: g1 = dinv * sum_ks part[ks] ----------------

__global__ void __launch_bounds__(256) g1red_kernel(const float* __restrict__ part,
                                                    const float* __restrict__ dinv,
                                                    float* __restrict__ g1, int N) {
    int t = blockIdx.x * 256 + threadIdx.x;       // float4 index over N*16 floats
    int total = N * H_DIM / 4;                    // 400000
    if (t >= total) return;
    const float4* p = (const float4*)part;
    float4 a = p[t];
    float4 b = p[t + (size_t)total];
    float4 c = p[t + (size_t)2 * total];
    float4 d = p[t + (size_t)3 * total];
    float di = dinv[t >> 2];                      // 4 float4 per node
    ((float4*)g1)[t] = make_float4(di * (((a.x + b.x) + c.x) + d.x),
                                   di * (((a.y + b.y) + c.y) + d.y),
                                   di * (((a.z + b.z) + c.z) + d.z),
                                   di * (((a.w + b.w) + c.w) + d.w));
}

// ---------------- layer 1 aggregation: g2 = dinv * relu(dinv*(sum + self) + b1) ----------------

__global__ void __launch_bounds__(256) agg1_kernel(const int* __restrict__ R,
                                                   const int* __restrict__ eidx,
                                                   const float* __restrict__ g1,
                                                   const float* __restrict__ dinv,
                                                   const float* __restrict__ b1,
                                                   float* __restrict__ g2, int N) {
    int t = blockIdx.x * 256 + threadIdx.x;
    int n = t >> 4;
    if (n >= N) return;
    int k = t & 15;
    int lo = R[n], hi = R[n + 1];
    float sum = g1[t];  // self-loop (g1 = dinv*h1)
    int e = lo;
    for (; e + 8 <= hi; e += 8) {
        int s[8];
        float v[8];
#pragma unroll
        for (int u = 0; u < 8; u++) s[u] = eidx[e + u];
#pragma unroll
        for (int u = 0; u < 8; u++) v[u] = g1[s[u] * H_DIM + k];
#pragma unroll
        for (int u = 0; u < 8; u++) sum += v[u];
    }
    for (; e < hi; ++e) sum += g1[eidx[e] * H_DIM + k];
    float di = dinv[n];
    g2[t] = di * fmaxf(di * sum + b1[k], 0.0f);
}

// ---------------- fused layer-2 aggregation + logits + log_softmax ----------------
// Phase 1 (= old agg2): 16 threads/node gather-sum g2 over the node's edge list; v = dinv*sum
// kept in LDS. Phase 2: 16 lanes/node compute classes {j, j+16, j+32}; max/lse via 16-lane
// butterfly shfl (groups are lane-aligned within the 64-wave). Saves the 6.4 MB s2
// round-trip and one launch. max-reduce exactly associative; lse tree-sum ~1e-6 reorder.

__global__ void __launch_bounds__(256) fin2_kernel(const int* __restrict__ R,
                                                   const int* __restrict__ eidx,
                                                   const float* __restrict__ g2,
                                                   const float* __restrict__ dinv,
                                                   const float* __restrict__ W2,
                                                   const float* __restrict__ b2,
                                                   float* __restrict__ out, int N) {
    __shared__ float w2s[H_DIM * C_DIM];
    __shared__ float b2s[C_DIM];
    __shared__ float vsh[16][17];
    for (int i = threadIdx.x; i < H_DIM * C_DIM; i += 256) w2s[i] = W2[i];
    if (threadIdx.x < C_DIM) b2s[threadIdx.x] = b2[threadIdx.x];

    int t = blockIdx.x * 256 + threadIdx.x;
    int n = t >> 4;                               // N = 100000 = 6250*16 -> always < N
    int k = t & 15;
    int lo = R[n], hi = R[n + 1];
    float sum = g2[t];                            // self-loop
    int e = lo;
    for (; e + 8 <= hi; e += 8) {
        int s[8];
        float v[8];
#pragma unroll
        for (int u = 0; u < 8; u++) s[u] = eidx[e + u];
#pragma unroll
        for (int u = 0; u < 8; u++) v[u] = g2[s[u] * H_DIM + k];
#pragma unroll
        for (int u = 0; u < 8; u++) sum += v[u];
    }
    for (; e < hi; ++e) sum += g2[eidx[e] * H_DIM + k];
    vsh[threadIdx.x >> 4][k] = dinv[n] * sum;
    __syncthreads();                              // also covers w2s/b2s

    int g = threadIdx.x >> 4;
    int j = threadIdx.x & 15;
    const float* v = vsh[g];
    int c2 = (j < 8) ? 32 + j : j;                // safe dummy column for j>=8
    float lg0 = b2s[j];
    float lg1 = b2s[j + 16];
    float lg2 = (j < 8) ? b2s[32 + j] : -1e30f;
    float lg2acc = 0.0f;
#pragma unroll
    for (int kk = 0; kk < H_DIM; ++kk) {
        float vk = v[kk];
        lg0 += vk * w2s[kk * C_DIM + j];
        lg1 += vk * w2s[kk * C_DIM + j + 16];
        lg2acc += vk * w2s[kk * C_DIM + c2];
    }
    if (j < 8) lg2 += lg2acc;                     // j>=8: lg2 stays -1e30 (ignored)

    float m = fmaxf(fmaxf(lg0, lg1), lg2);
#pragma unroll
    for (int s = 1; s < 16; s <<= 1) m = fmaxf(m, __shfl_xor(m, s, 64));
    float ss = __expf(lg0 - m) + __expf(lg1 - m) + ((j < 8) ? __expf(lg2 - m) : 0.0f);
#pragma unroll
    for (int s = 1; s < 16; s <<= 1) ss += __shfl_xor(ss, s, 64);
    float lse = m + __logf(ss);

    size_t base = (size_t)n * C_DIM;
    size_t lim = (size_t)N * C_DIM;
    out[base + j] = lg0 - lse;
    out[base + 16 + j] = lg1 - lse;
    if (j < 8) out[base + 32 + j] = lg2 - lse;
    out[lim + base + j] = lg0;
    out[lim + base + 16 + j] = lg1;
    if (j < 8) out[lim + base + 32 + j] = lg2;
}

// ---------------- launch ----------------

extern "C" void kernel_launch(void* const* d_in, const int* in_sizes, int n_in,
                              void* d_out, int out_size, void* d_ws, size_t ws_size,
                              hipStream_t stream) {
    const float* x  = (const float*)d_in[0];
    const int* ei   = (const int*)d_in[1];
    const float* W1 = (const float*)d_in[2];
    const float* b1 = (const float*)d_in[3];
    const float* W2 = (const float*)d_in[4];
    const float* b2 = (const float*)d_in[5];
    float* out = (float*)d_out;

    const int N = N_NODES;
    const int E = in_sizes[1] / 2;
    const int* src = ei;
    const int* dst = ei + E;

    // ws layout (ints): R[N+16] | BC[512] | BO[256] | cursor[256] | dinv[N+16] | eidx[E] |
    //                   union{ packed[E] | g1[16N] + g2[16N] } | part[4*16N]
    int* R      = (int*)d_ws;                 // CSR node offsets (R[N] = E)
    int* BC     = R + 100016;                 // bucket counts
    int* BO     = BC + 512;                   // bucket offsets (exclusive scan)
    int* cursor = BO + 256;
    float* dinv = (float*)(cursor + 256);
    int* eidx   = (int*)(dinv + 100016);
    int* packed = eidx + E;                   // dead after sort2_kernel
    float* g1   = (float*)packed;             // reuses packed region
    float* g2   = g1 + 16 * N;
    float* part = g2 + 16 * N;                // 4 partial planes (split-K)

    const int NB = (N + 255) / 256;  // 391
    const int NCH = (E + CHUNK - 1) / CHUNK;

    hipMemsetAsync(BC, 0, NBUCK * sizeof(int), stream);
    bhist_kernel<<<NCH, 256, 0, stream>>>(dst, BC, E);
    bscan_kernel<<<1, 256, 0, stream>>>(BC, BO, cursor, R, E, N);
    partition_kernel<<<NCH, 256, 0, stream>>>(src, dst, cursor, packed, E);
    sort2_kernel<<<NBUCK, 1024, 0, stream>>>(BO, packed, R, dinv, eidx, N);

    gemm1p_kernel<<<NB * KSPLIT, 256, 0, stream>>>(x, W1, part, N);
    g1red_kernel<<<(N * H_DIM / 4 + 255) / 256, 256, 0, stream>>>(part, dinv, g1, N);
    agg1_kernel<<<(N * 16 + 255) / 256, 256, 0, stream>>>(R, eidx, g1, dinv, b1, g2, N);
    fin2_kernel<<<N / 16, 256, 0, stream>>>(R, eidx, g2, dinv, W2, b2, out, N);
}

// Round 8
// 518.192 us; speedup vs baseline: 1.2502x; 1.0241x over previous
//
#include <hip/hip_runtime.h>
#include <hip/hip_bf16.h>
#include <math.h>

#define N_NODES 100000
#define F_IN 512
#define H_DIM 16
#define C_DIM 40

#define BSHIFT 9                       // 512 nodes per bucket
#define BNODES 512
#define NBUCK 196                      // ceil(100000 / 512)
#define CHUNK 8192                     // edges per partition block
#define SRC_MASK 0x1FFFF               // 17 bits (N < 131072)
#define SORT_CAP 18432                 // LDS stage capacity (mean bucket 16.3K + 16 sigma)

#define KSPLIT 4
#define KSEG (F_IN / KSPLIT)           // 128 floats = 4 groups of 32

// ---------------- bucket histogram (196 bins) ----------------

__global__ void __launch_bounds__(256) bhist_kernel(const int* __restrict__ dst,
                                                    int* __restrict__ BC, int E) {
    __shared__ int cnt[NBUCK];
    int start = blockIdx.x * CHUNK;
    int end = start + CHUNK < E ? start + CHUNK : E;
    for (int i = threadIdx.x; i < NBUCK; i += 256) cnt[i] = 0;
    __syncthreads();
    for (int i = start + threadIdx.x; i < end; i += 256)
        atomicAdd(&cnt[dst[i] >> BSHIFT], 1);
    __syncthreads();
    for (int i = threadIdx.x; i < NBUCK; i += 256) {
        int c = cnt[i];
        if (c) atomicAdd(&BC[i], c);
    }
}

// ---------------- scan of 196 bucket counts -> BO / cursor; R[N]=E ----------------

__global__ void __launch_bounds__(256) bscan_kernel(const int* __restrict__ BC,
                                                    int* __restrict__ BO,
                                                    int* __restrict__ cursor,
                                                    int* __restrict__ R, int E, int N) {
    __shared__ int buf[2][256];
    int tid = threadIdx.x;
    int v = (tid < NBUCK) ? BC[tid] : 0;
    int cur = 0;
    buf[0][tid] = v;
    __syncthreads();
    for (int off = 1; off < 256; off <<= 1) {
        int t = buf[cur][tid] + ((tid >= off) ? buf[cur][tid - off] : 0);
        cur ^= 1;
        buf[cur][tid] = t;
        __syncthreads();
    }
    int excl = buf[cur][tid] - v;                 // exclusive prefix
    if (tid <= NBUCK) {                           // tid==NBUCK -> total == E
        BO[tid] = excl;
        if (tid < NBUCK) cursor[tid] = excl;
    }
    if (tid == 0) R[N] = E;
}

// ---------------- radix partition by dst bucket; packed = (local_dst<<17)|src ----------------
// v2: scatter into bucket-ordered LDS stage, then COALESCED copy-out (run found via
// binary search in the block-local prefix). Kills partial-line write amplification
// (~53 distinct 64B lines per wave-store -> consecutive lanes, consecutive addresses).

__global__ void __launch_bounds__(256) partition_kernel(const int* __restrict__ src,
                                                        const int* __restrict__ dst,
                                                        int* __restrict__ cursor,
                                                        int* __restrict__ packed, int E) {
    __shared__ int cnt[NBUCK];
    __shared__ int base[NBUCK];
    __shared__ int lpre[NBUCK + 1];
    __shared__ int sbuf[2][256];
    __shared__ int stage[CHUNK];                  // 32 KB
    int tid = threadIdx.x;
    int start = blockIdx.x * CHUNK;
    int end = start + CHUNK < E ? start + CHUNK : E;
    int nch = end - start;
    for (int i = tid; i < NBUCK; i += 256) cnt[i] = 0;
    __syncthreads();
    for (int i = start + tid; i < end; i += 256)
        atomicAdd(&cnt[dst[i] >> BSHIFT], 1);
    __syncthreads();
    // block-local exclusive prefix of the 196 counts (256-wide Hillis-Steele)
    int v = (tid < NBUCK) ? cnt[tid] : 0;
    int cur = 0;
    sbuf[0][tid] = v;
    __syncthreads();
    for (int off = 1; off < 256; off <<= 1) {
        int t = sbuf[cur][tid] + ((tid >= off) ? sbuf[cur][tid - off] : 0);
        cur ^= 1;
        sbuf[cur][tid] = t;
        __syncthreads();
    }
    if (tid < NBUCK) {
        lpre[tid] = sbuf[cur][tid] - v;           // exclusive
        base[tid] = v ? atomicAdd(&cursor[tid], v) : 0;
        cnt[tid] = 0;                             // reuse as local position
    }
    if (tid == 0) lpre[NBUCK] = nch;
    __syncthreads();
    // scatter into LDS, bucket-ordered
    for (int i = start + tid; i < end; i += 256) {
        int d = dst[i];
        int b = d >> BSHIFT;
        int p = lpre[b] + atomicAdd(&cnt[b], 1);
        stage[p] = ((d & (BNODES - 1)) << 17) | src[i];
    }
    __syncthreads();
    // coalesced copy-out: consecutive j -> consecutive global addresses within each run
    for (int j = tid; j < nch; j += 256) {
        int loB = 0, hiB = NBUCK;                 // find b: lpre[b] <= j < lpre[b+1]
        while (hiB - loB > 1) {
            int mid = (loB + hiB) >> 1;
            if (lpre[mid] <= j) loB = mid; else hiB = mid;
        }
        packed[base[loB] + (j - lpre[loB])] = stage[j];
    }
}

// ---------------- per-bucket: degree hist + scan -> R/dinv, then counting scatter -> eidx ----------------
// v2: eidx scatter lands in a 72 KB LDS stage (bucket-local positions), then a
// coalesced linear copy to global. Fallback to direct scatter if a bucket exceeds
// SORT_CAP (never for uniform-random dst; correctness guard only).

__global__ void __launch_bounds__(1024) sort2_kernel(const int* __restrict__ BO,
                                                     const int* __restrict__ packed,
                                                     int* __restrict__ R,
                                                     float* __restrict__ dinv,
                                                     int* __restrict__ eidx, int N) {
    __shared__ int cnt[BNODES];
    __shared__ int buf[2][BNODES];
    __shared__ int stage[SORT_CAP];               // 72 KB
    int b = blockIdx.x;
    int tid = threadIdx.x;
    int lo = BO[b], hi = BO[b + 1];
    int len = hi - lo;
    if (tid < BNODES) cnt[tid] = 0;
    __syncthreads();
    // pass 1: per-node degree histogram in LDS
    for (int e = lo + tid; e < hi; e += 1024)
        atomicAdd(&cnt[packed[e] >> 17], 1);
    __syncthreads();
    int deg = (tid < BNODES) ? cnt[tid] : 0;
    // 512-wide Hillis-Steele inclusive scan -> exclusive offsets (tid<512 active)
    int cur = 0;
    if (tid < BNODES) buf[0][tid] = deg;
    __syncthreads();
    for (int off = 1; off < BNODES; off <<= 1) {
        int t = 0;
        if (tid < BNODES) t = buf[cur][tid] + ((tid >= off) ? buf[cur][tid - off] : 0);
        cur ^= 1;
        if (tid < BNODES) buf[cur][tid] = t;
        __syncthreads();
    }
    if (tid < BNODES) {
        int excl = buf[cur][tid] - deg;           // bucket-LOCAL exclusive offset
        int n = (b << BSHIFT) + tid;
        if (n < N) {
            R[n] = lo + excl;                     // global CSR offset
            dinv[n] = rsqrtf((float)(deg + 1));   // +1 = self-loop
        }
        cnt[tid] = excl;                          // reuse as bucket-local cursor
    }
    __syncthreads();
    if (len <= SORT_CAP) {
        // pass 2: counting scatter into LDS stage
        for (int e = lo + tid; e < hi; e += 1024) {
            int p = packed[e];
            int pos = atomicAdd(&cnt[p >> 17], 1);
            stage[pos] = p & SRC_MASK;
        }
        __syncthreads();
        // pass 3: coalesced linear copy-out
        for (int j = tid; j < len; j += 1024) eidx[lo + j] = stage[j];
    } else {
        // fallback: direct scatter (bucket-local cursor + lo)
        for (int e = lo + tid; e < hi; e += 1024) {
            int p = packed[e];
            int pos = atomicAdd(&cnt[p >> 17], 1);
            eidx[lo + pos] = p & SRC_MASK;
        }
    }
}

// ---------------- GEMM1 (split-K): part[ks] = x[:, ks*128:(ks+1)*128] @ W1[seg] ----------------
// 256-thread blocks (1564 WGs), 2 groups of 32 floats (8 float4) in flight per lane,
// W read wave-uniform from global (scalar cache). Per-thread summation order identical
// to previous round -> partials bit-identical.

#define G1_ISSUE(BUF, G)                                             \
    {                                                                \
        _Pragma("unroll")                                            \
        for (int p = 0; p < 8; ++p) BUF[p] = xr[(G) * 8 + p];        \
    }

#define G1_COMPUTE(BUF, G)                                           \
    {                                                                \
        const float* xf = (const float*)(BUF);                       \
        _Pragma("unroll")                                            \
        for (int j = 0; j < 32; ++j) {                               \
            float s = xf[j];                                         \
            const float4* Wj = (const float4*)(Wb + ((G) * 32 + j) * H_DIM); \
            _Pragma("unroll")                                        \
            for (int p = 0; p < 4; ++p) {                            \
                float4 wv = Wj[p];                                   \
                acc[4 * p + 0] += s * wv.x;                          \
                acc[4 * p + 1] += s * wv.y;                          \
                acc[4 * p + 2] += s * wv.z;                          \
                acc[4 * p + 3] += s * wv.w;                          \
            }                                                        \
        }                                                            \
    }

__global__ void __launch_bounds__(256) gemm1p_kernel(const float* __restrict__ x,
                                                     const float* __restrict__ W1,
                                                     float* __restrict__ part, int N) {
    int bid = blockIdx.x;
    int ks = bid & (KSPLIT - 1);                  // consecutive blocks: same rows, diff K-seg
    int rb = bid >> 2;
    int row = rb * 256 + threadIdx.x;
    int cr = row < N ? row : N - 1;               // tail lanes re-read row N-1 (discarded)
    const float4* xr = (const float4*)(x + (size_t)cr * F_IN + ks * KSEG);
    const float* Wb = W1 + ks * KSEG * H_DIM;

    float4 bufA[8], bufB[8];
    float acc[H_DIM];
#pragma unroll
    for (int k = 0; k < H_DIM; k++) acc[k] = 0.0f;

    G1_ISSUE(bufA, 0);
    G1_ISSUE(bufB, 1);            // 2 groups (256 B/lane) in flight
    G1_COMPUTE(bufA, 0);
    G1_ISSUE(bufA, 2);
    G1_COMPUTE(bufB, 1);
    G1_ISSUE(bufB, 3);
    G1_COMPUTE(bufA, 2);
    G1_COMPUTE(bufB, 3);

    if (row < N) {
        float4* o = (float4*)(part + (size_t)ks * N * H_DIM + (size_t)row * H_DIM);
#pragma unroll
        for (int p = 0; p < 4; p++)
            o[p] = make_float4(acc[4 * p], acc[4 * p + 1], acc[4 * p + 2], acc[4 * p + 3]);
    }
}

// ---------------- reduce 4 partial planes, apply dinv: g1 = dinv * sum_ks part[ks] ----------------

__global__ void __launch_bounds__(256) g1red_kernel(const float* __restrict__ part,
                                                    const float* __restrict__ dinv,
                                                    float* __restrict__ g1, int N) {
    int t = blockIdx.x * 256 + threadIdx.x;       // float4 index over N*16 floats
    int total = N * H_DIM / 4;                    // 400000
    if (t >= total) return;
    const float4* p = (const float4*)part;
    float4 a = p[t];
    float4 b = p[t + (size_t)total];
    float4 c = p[t + (size_t)2 * total];
    float4 d = p[t + (size_t)3 * total];
    float di = dinv[t >> 2];                      // 4 float4 per node
    ((float4*)g1)[t] = make_float4(di * (((a.x + b.x) + c.x) + d.x),
                                   di * (((a.y + b.y) + c.y) + d.y),
                                   di * (((a.z + b.z) + c.z) + d.z),
                                   di * (((a.w + b.w) + c.w) + d.w));
}

// ---------------- layer 1 aggregation: g2 = dinv * relu(dinv*(sum + self) + b1) ----------------

__global__ void __launch_bounds__(256) agg1_kernel(const int* __restrict__ R,
                                                   const int* __restrict__ eidx,
                                                   const float* __restrict__ g1,
                                                   const float* __restrict__ dinv,
                                                   const float* __restrict__ b1,
                                                   float* __restrict__ g2, int N) {
    int t = blockIdx.x * 256 + threadIdx.x;
    int n = t >> 4;
    if (n >= N) return;
    int k = t & 15;
    int lo = R[n], hi = R[n + 1];
    float sum = g1[t];  // self-loop (g1 = dinv*h1)
    int e = lo;
    for (; e + 8 <= hi; e += 8) {
        int s[8];
        float v[8];
#pragma unroll
        for (int u = 0; u < 8; u++) s[u] = eidx[e + u];
#pragma unroll
        for (int u = 0; u < 8; u++) v[u] = g1[s[u] * H_DIM + k];
#pragma unroll
        for (int u = 0; u < 8; u++) sum += v[u];
    }
    for (; e < hi; ++e) sum += g1[eidx[e] * H_DIM + k];
    float di = dinv[n];
    g2[t] = di * fmaxf(di * sum + b1[k], 0.0f);
}

// ---------------- fused layer-2 aggregation + logits + log_softmax ----------------

__global__ void __launch_bounds__(256) fin2_kernel(const int* __restrict__ R,
                                                   const int* __restrict__ eidx,
                                                   const float* __restrict__ g2,
                                                   const float* __restrict__ dinv,
                                                   const float* __restrict__ W2,
                                                   const float* __restrict__ b2,
                                                   float* __restrict__ out, int N) {
    __shared__ float w2s[H_DIM * C_DIM];
    __shared__ float b2s[C_DIM];
    __shared__ float vsh[16][17];
    for (int i = threadIdx.x; i < H_DIM * C_DIM; i += 256) w2s[i] = W2[i];
    if (threadIdx.x < C_DIM) b2s[threadIdx.x] = b2[threadIdx.x];

    int t = blockIdx.x * 256 + threadIdx.x;
    int n = t >> 4;                               // N = 100000 = 6250*16 -> always < N
    int k = t & 15;
    int lo = R[n], hi = R[n + 1];
    float sum = g2[t];                            // self-loop
    int e = lo;
    for (; e + 8 <= hi; e += 8) {
        int s[8];
        float v[8];
#pragma unroll
        for (int u = 0; u < 8; u++) s[u] = eidx[e + u];
#pragma unroll
        for (int u = 0; u < 8; u++) v[u] = g2[s[u] * H_DIM + k];
#pragma unroll
        for (int u = 0; u < 8; u++) sum += v[u];
    }
    for (; e < hi; ++e) sum += g2[eidx[e] * H_DIM + k];
    vsh[threadIdx.x >> 4][k] = dinv[n] * sum;
    __syncthreads();                              // also covers w2s/b2s

    int g = threadIdx.x >> 4;
    int j = threadIdx.x & 15;
    const float* v = vsh[g];
    int c2 = (j < 8) ? 32 + j : j;                // safe dummy column for j>=8
    float lg0 = b2s[j];
    float lg1 = b2s[j + 16];
    float lg2 = (j < 8) ? b2s[32 + j] : -1e30f;
    float lg2acc = 0.0f;
#pragma unroll
    for (int kk = 0; kk < H_DIM; ++kk) {
        float vk = v[kk];
        lg0 += vk * w2s[kk * C_DIM + j];
        lg1 += vk * w2s[kk * C_DIM + j + 16];
        lg2acc += vk * w2s[kk * C_DIM + c2];
    }
    if (j < 8) lg2 += lg2acc;                     // j>=8: lg2 stays -1e30 (ignored)

    float m = fmaxf(fmaxf(lg0, lg1), lg2);
#pragma unroll
    for (int s = 1; s < 16; s <<= 1) m = fmaxf(m, __shfl_xor(m, s, 64));
    float ss = __expf(lg0 - m) + __expf(lg1 - m) + ((j < 8) ? __expf(lg2 - m) : 0.0f);
#pragma unroll
    for (int s = 1; s < 16; s <<= 1) ss += __shfl_xor(ss, s, 64);
    float lse = m + __logf(ss);

    size_t base = (size_t)n * C_DIM;
    size_t lim = (size_t)N * C_DIM;
    out[base + j] = lg0 - lse;
    out[base + 16 + j] = lg1 - lse;
    if (j < 8) out[base + 32 + j] = lg2 - lse;
    out[lim + base + j] = lg0;
    out[lim + base + 16 + j] = lg1;
    if (j < 8) out[lim + base + 32 + j] = lg2;
}

// ---------------- launch ----------------

extern "C" void kernel_launch(void* const* d_in, const int* in_sizes, int n_in,
                              void* d_out, int out_size, void* d_ws, size_t ws_size,
                              hipStream_t stream) {
    const float* x  = (const float*)d_in[0];
    const int* ei   = (const int*)d_in[1];
    const float* W1 = (const float*)d_in[2];
    const float* b1 = (const float*)d_in[3];
    const float* W2 = (const float*)d_in[4];
    const float* b2 = (const float*)d_in[5];
    float* out = (float*)d_out;

    const int N = N_NODES;
    const int E = in_sizes[1] / 2;
    const int* src = ei;
    const int* dst = ei + E;

    // ws layout (ints): R[N+16] | BC[512] | BO[256] | cursor[256] | dinv[N+16] | eidx[E] |
    //                   union{ packed[E] | g1[16N] + g2[16N] } | part[4*16N]
    int* R      = (int*)d_ws;                 // CSR node offsets (R[N] = E)
    int* BC     = R + 100016;                 // bucket counts
    int* BO     = BC + 512;                   // bucket offsets (exclusive scan)
    int* cursor = BO + 256;
    float* dinv = (float*)(cursor + 256);
    int* eidx   = (int*)(dinv + 100016);
    int* packed = eidx + E;                   // dead after sort2_kernel
    float* g1   = (float*)packed;             // reuses packed region
    float* g2   = g1 + 16 * N;
    float* part = g2 + 16 * N;                // 4 partial planes (split-K)

    const int NB = (N + 255) / 256;  // 391
    const int NCH = (E + CHUNK - 1) / CHUNK;

    hipMemsetAsync(BC, 0, NBUCK * sizeof(int), stream);
    bhist_kernel<<<NCH, 256, 0, stream>>>(dst, BC, E);
    bscan_kernel<<<1, 256, 0, stream>>>(BC, BO, cursor, R, E, N);
    partition_kernel<<<NCH, 256, 0, stream>>>(src, dst, cursor, packed, E);
    sort2_kernel<<<NBUCK, 1024, 0, stream>>>(BO, packed, R, dinv, eidx, N);

    gemm1p_kernel<<<NB * KSPLIT, 256, 0, stream>>>(x, W1, part, N);
    g1red_kernel<<<(N * H_DIM / 4 + 255) / 256, 256, 0, stream>>>(part, dinv, g1, N);
    agg1_kernel<<<(N * 16 + 255) / 256, 256, 0, stream>>>(R, eidx, g1, dinv, b1, g2, N);
    fin2_kernel<<<N / 16, 256, 0, stream>>>(R, eidx, g2, dinv, W2, b2, out, N);
}

// Round 9
// 483.231 us; speedup vs baseline: 1.3406x; 1.0724x over previous
//
#include <hip/hip_runtime.h>
#include <hip/hip_bf16.h>
#include <math.h>

#define N_NODES 100000
#define F_IN 512
#define H_DIM 16
#define C_DIM 40

#define BSHIFT 9                       // 512 nodes per bucket
#define BNODES 512
#define NBUCK 196                      // ceil(100000 / 512)
#define CHUNK4 4096                    // edges per partition block (16 KB LDS stage)
#define SRC_MASK 0x1FFFF               // 17 bits (N < 131072)
#define CAP 20480                      // fixed bucket capacity (+32 sigma over 16384 mean)
#define SORT_CAP 18432                 // sort LDS stage capacity (fallback above)

#define KSPLIT 4
#define KSEG (F_IN / KSPLIT)           // 128 floats = 4 groups of 32

// ================= K1: partition (fixed-cap buckets) PARALLEL gemm1p ==================
// Blocks [0, NCH4): radix partition by dst bucket into CAP-padded regions; LDS-staged
//   scatter + coalesced copy-out (R6-verified pattern). Fixed-capacity bases remove the
//   need for bhist/bscan (no global prefix).
// Blocks [NCH4, ...): split-K GEMM x@W1 (register ping-pong, W via scalar cache).
// The two halves are data-independent; co-residency overlaps edge prep with the GEMM.

#define G1_ISSUE(BUF, G)                                             \
    {                                                                \
        _Pragma("unroll")                                            \
        for (int p = 0; p < 8; ++p) BUF[p] = xr[(G) * 8 + p];        \
    }

#define G1_COMPUTE(BUF, G)                                           \
    {                                                                \
        const float* xf = (const float*)(BUF);                       \
        _Pragma("unroll")                                            \
        for (int j = 0; j < 32; ++j) {                               \
            float s = xf[j];                                         \
            const float4* Wj = (const float4*)(Wb + ((G) * 32 + j) * H_DIM); \
            _Pragma("unroll")                                        \
            for (int p = 0; p < 4; ++p) {                            \
                float4 wv = Wj[p];                                   \
                acc[4 * p + 0] += s * wv.x;                          \
                acc[4 * p + 1] += s * wv.y;                          \
                acc[4 * p + 2] += s * wv.z;                          \
                acc[4 * p + 3] += s * wv.w;                          \
            }                                                        \
        }                                                            \
    }

__global__ void __launch_bounds__(256) k1_kernel(const int* __restrict__ src,
                                                 const int* __restrict__ dst,
                                                 int* __restrict__ cursor,
                                                 int* __restrict__ packed,
                                                 const float* __restrict__ x,
                                                 const float* __restrict__ W1,
                                                 float* __restrict__ part,
                                                 int E, int N, int NCH4) {
    // static LDS (20.3 KB) shared by all blocks; only partition blocks touch it
    __shared__ int cnt[NBUCK];
    __shared__ int base[NBUCK];
    __shared__ int lpre[NBUCK + 1];
    __shared__ int sbuf[2][256];
    __shared__ int stage[CHUNK4];

    if ((int)blockIdx.x < NCH4) {
        // ---------------- partition branch ----------------
        int tid = threadIdx.x;
        int start = blockIdx.x * CHUNK4;
        int end = start + CHUNK4 < E ? start + CHUNK4 : E;
        int nch = end - start;
        for (int i = tid; i < NBUCK; i += 256) cnt[i] = 0;
        __syncthreads();
        for (int i = start + tid; i < end; i += 256)
            atomicAdd(&cnt[dst[i] >> BSHIFT], 1);
        __syncthreads();
        // block-local exclusive prefix of the 196 counts
        int v = (tid < NBUCK) ? cnt[tid] : 0;
        int cur = 0;
        sbuf[0][tid] = v;
        __syncthreads();
        for (int off = 1; off < 256; off <<= 1) {
            int t = sbuf[cur][tid] + ((tid >= off) ? sbuf[cur][tid - off] : 0);
            cur ^= 1;
            sbuf[cur][tid] = t;
            __syncthreads();
        }
        if (tid < NBUCK) {
            lpre[tid] = sbuf[cur][tid] - v;       // exclusive
            base[tid] = tid * CAP + (v ? atomicAdd(&cursor[tid], v) : 0);
            cnt[tid] = 0;                         // reuse as local position
        }
        if (tid == 0) lpre[NBUCK] = nch;
        __syncthreads();
        // scatter into LDS, bucket-ordered
        for (int i = start + tid; i < end; i += 256) {
            int d = dst[i];
            int b = d >> BSHIFT;
            int p = lpre[b] + atomicAdd(&cnt[b], 1);
            stage[p] = ((d & (BNODES - 1)) << 17) | src[i];
        }
        __syncthreads();
        // coalesced copy-out
        for (int j = tid; j < nch; j += 256) {
            int loB = 0, hiB = NBUCK;             // find b: lpre[b] <= j < lpre[b+1]
            while (hiB - loB > 1) {
                int mid = (loB + hiB) >> 1;
                if (lpre[mid] <= j) loB = mid; else hiB = mid;
            }
            packed[base[loB] + (j - lpre[loB])] = stage[j];
        }
    } else {
        // ---------------- gemm branch ----------------
        int bid = blockIdx.x - NCH4;
        int ks = bid & (KSPLIT - 1);
        int rb = bid >> 2;
        int row = rb * 256 + threadIdx.x;
        int cr = row < N ? row : N - 1;
        const float4* xr = (const float4*)(x + (size_t)cr * F_IN + ks * KSEG);
        const float* Wb = W1 + ks * KSEG * H_DIM;

        float4 bufA[8], bufB[8];
        float acc[H_DIM];
#pragma unroll
        for (int k = 0; k < H_DIM; k++) acc[k] = 0.0f;

        G1_ISSUE(bufA, 0);
        G1_ISSUE(bufB, 1);
        G1_COMPUTE(bufA, 0);
        G1_ISSUE(bufA, 2);
        G1_COMPUTE(bufB, 1);
        G1_ISSUE(bufB, 3);
        G1_COMPUTE(bufA, 2);
        G1_COMPUTE(bufB, 3);

        if (row < N) {
            float4* o = (float4*)(part + (size_t)ks * N * H_DIM + (size_t)row * H_DIM);
#pragma unroll
            for (int p = 0; p < 4; p++)
                o[p] = make_float4(acc[4 * p], acc[4 * p + 1], acc[4 * p + 2], acc[4 * p + 3]);
        }
    }
}

// ================= K2: per-bucket sort PARALLEL g1 reduction ==================
// Blocks [0, NBUCK): degree hist + scan -> R/R2/dinv, LDS-staged counting scatter ->
//   CAP-padded eidx (coalesced copy-out; direct-scatter fallback above SORT_CAP).
// Blocks [NBUCK, ...): g1' = sum of 4 split-K partial planes (NO dinv — folded into agg1).

__global__ void __launch_bounds__(1024) k2_kernel(const int* __restrict__ cursor,
                                                  const int* __restrict__ packed,
                                                  int* __restrict__ R,
                                                  int* __restrict__ R2,
                                                  float* __restrict__ dinv,
                                                  int* __restrict__ eidx,
                                                  const float* __restrict__ part,
                                                  float* __restrict__ g1, int N) {
    __shared__ int cnt[BNODES];
    __shared__ int buf[2][BNODES];
    __shared__ int stage[SORT_CAP];               // 72 KB (78 KB total -> 2 WGs/CU = 32 waves)

    if (blockIdx.x < NBUCK) {
        // ---------------- sort branch ----------------
        int b = blockIdx.x;
        int tid = threadIdx.x;
        int lo = b * CAP;
        int len = cursor[b];
        int hi = lo + len;
        if (tid < BNODES) cnt[tid] = 0;
        __syncthreads();
        for (int e = lo + tid; e < hi; e += 1024)
            atomicAdd(&cnt[packed[e] >> 17], 1);
        __syncthreads();
        int deg = (tid < BNODES) ? cnt[tid] : 0;
        int cur = 0;
        if (tid < BNODES) buf[0][tid] = deg;
        __syncthreads();
        for (int off = 1; off < BNODES; off <<= 1) {
            int t = 0;
            if (tid < BNODES) t = buf[cur][tid] + ((tid >= off) ? buf[cur][tid - off] : 0);
            cur ^= 1;
            if (tid < BNODES) buf[cur][tid] = t;
            __syncthreads();
        }
        if (tid < BNODES) {
            int excl = buf[cur][tid] - deg;       // bucket-local exclusive offset
            int n = (b << BSHIFT) + tid;
            if (n < N) {
                R[n] = lo + excl;                 // padded-eidx CSR offset
                R2[n] = lo + excl + deg;          // per-node end (padded layout breaks R[n+1])
                dinv[n] = rsqrtf((float)(deg + 1));
            }
            cnt[tid] = excl;                      // reuse as bucket-local cursor
        }
        __syncthreads();
        if (len <= SORT_CAP) {
            for (int e = lo + tid; e < hi; e += 1024) {
                int p = packed[e];
                int pos = atomicAdd(&cnt[p >> 17], 1);
                stage[pos] = p & SRC_MASK;
            }
            __syncthreads();
            for (int j = tid; j < len; j += 1024) eidx[lo + j] = stage[j];
        } else {
            for (int e = lo + tid; e < hi; e += 1024) {
                int p = packed[e];
                int pos = atomicAdd(&cnt[p >> 17], 1);
                eidx[lo + pos] = p & SRC_MASK;
            }
        }
    } else {
        // ---------------- g1 reduce branch (no dinv) ----------------
        int t = (blockIdx.x - NBUCK) * 1024 + threadIdx.x;
        int total = N * H_DIM / 4;                // 400000 float4
        if (t < total) {
            const float4* p = (const float4*)part;
            float4 a = p[t];
            float4 b = p[t + (size_t)total];
            float4 c = p[t + (size_t)2 * total];
            float4 d = p[t + (size_t)3 * total];
            ((float4*)g1)[t] = make_float4((((a.x + b.x) + c.x) + d.x),
                                           (((a.y + b.y) + c.y) + d.y),
                                           (((a.z + b.z) + c.z) + d.z),
                                           (((a.w + b.w) + c.w) + d.w));
        }
    }
}

// ---------------- layer 1 aggregation: g2 = dinv*relu(dinv*(sum dinv[s]*h[s] + self) + b1) ----------------

__global__ void __launch_bounds__(256) agg1_kernel(const int* __restrict__ R,
                                                   const int* __restrict__ R2,
                                                   const int* __restrict__ eidx,
                                                   const float* __restrict__ g1,
                                                   const float* __restrict__ dinv,
                                                   const float* __restrict__ b1,
                                                   float* __restrict__ g2, int N) {
    int t = blockIdx.x * 256 + threadIdx.x;
    int n = t >> 4;
    if (n >= N) return;
    int k = t & 15;
    int lo = R[n], hi = R2[n];
    float di = dinv[n];
    float sum = di * g1[t];                       // self-loop: dinv[n]*h[n]
    int e = lo;
    for (; e + 8 <= hi; e += 8) {
        int s[8];
        float dv[8];
        float v[8];
#pragma unroll
        for (int u = 0; u < 8; u++) s[u] = eidx[e + u];
#pragma unroll
        for (int u = 0; u < 8; u++) dv[u] = dinv[s[u]];
#pragma unroll
        for (int u = 0; u < 8; u++) v[u] = g1[s[u] * H_DIM + k];
#pragma unroll
        for (int u = 0; u < 8; u++) sum += v[u] * dv[u];
    }
    for (; e < hi; ++e) {
        int s = eidx[e];
        sum += g1[s * H_DIM + k] * dinv[s];
    }
    g2[t] = di * fmaxf(di * sum + b1[k], 0.0f);
}

// ---------------- fused layer-2 aggregation + logits + log_softmax ----------------

__global__ void __launch_bounds__(256) fin2_kernel(const int* __restrict__ R,
                                                   const int* __restrict__ R2,
                                                   const int* __restrict__ eidx,
                                                   const float* __restrict__ g2,
                                                   const float* __restrict__ dinv,
                                                   const float* __restrict__ W2,
                                                   const float* __restrict__ b2,
                                                   float* __restrict__ out, int N) {
    __shared__ float w2s[H_DIM * C_DIM];
    __shared__ float b2s[C_DIM];
    __shared__ float vsh[16][17];
    for (int i = threadIdx.x; i < H_DIM * C_DIM; i += 256) w2s[i] = W2[i];
    if (threadIdx.x < C_DIM) b2s[threadIdx.x] = b2[threadIdx.x];

    int t = blockIdx.x * 256 + threadIdx.x;
    int n = t >> 4;                               // N divisible by 16 -> always < N
    int k = t & 15;
    int lo = R[n], hi = R2[n];
    float sum = g2[t];                            // self-loop (g2 has dinv folded)
    int e = lo;
    for (; e + 8 <= hi; e += 8) {
        int s[8];
        float v[8];
#pragma unroll
        for (int u = 0; u < 8; u++) s[u] = eidx[e + u];
#pragma unroll
        for (int u = 0; u < 8; u++) v[u] = g2[s[u] * H_DIM + k];
#pragma unroll
        for (int u = 0; u < 8; u++) sum += v[u];
    }
    for (; e < hi; ++e) sum += g2[eidx[e] * H_DIM + k];
    vsh[threadIdx.x >> 4][k] = dinv[n] * sum;
    __syncthreads();                              // also covers w2s/b2s

    int g = threadIdx.x >> 4;
    int j = threadIdx.x & 15;
    const float* v = vsh[g];
    int c2 = (j < 8) ? 32 + j : j;                // safe dummy column for j>=8
    float lg0 = b2s[j];
    float lg1 = b2s[j + 16];
    float lg2 = (j < 8) ? b2s[32 + j] : -1e30f;
    float lg2acc = 0.0f;
#pragma unroll
    for (int kk = 0; kk < H_DIM; ++kk) {
        float vk = v[kk];
        lg0 += vk * w2s[kk * C_DIM + j];
        lg1 += vk * w2s[kk * C_DIM + j + 16];
        lg2acc += vk * w2s[kk * C_DIM + c2];
    }
    if (j < 8) lg2 += lg2acc;

    float m = fmaxf(fmaxf(lg0, lg1), lg2);
#pragma unroll
    for (int s = 1; s < 16; s <<= 1) m = fmaxf(m, __shfl_xor(m, s, 64));
    float ss = __expf(lg0 - m) + __expf(lg1 - m) + ((j < 8) ? __expf(lg2 - m) : 0.0f);
#pragma unroll
    for (int s = 1; s < 16; s <<= 1) ss += __shfl_xor(ss, s, 64);
    float lse = m + __logf(ss);

    size_t base = (size_t)n * C_DIM;
    size_t lim = (size_t)N * C_DIM;
    out[base + j] = lg0 - lse;
    out[base + 16 + j] = lg1 - lse;
    if (j < 8) out[base + 32 + j] = lg2 - lse;
    out[lim + base + j] = lg0;
    out[lim + base + 16 + j] = lg1;
    if (j < 8) out[lim + base + 32 + j] = lg2;
}

// ---------------- launch ----------------

extern "C" void kernel_launch(void* const* d_in, const int* in_sizes, int n_in,
                              void* d_out, int out_size, void* d_ws, size_t ws_size,
                              hipStream_t stream) {
    const float* x  = (const float*)d_in[0];
    const int* ei   = (const int*)d_in[1];
    const float* W1 = (const float*)d_in[2];
    const float* b1 = (const float*)d_in[3];
    const float* W2 = (const float*)d_in[4];
    const float* b2 = (const float*)d_in[5];
    float* out = (float*)d_out;

    const int N = N_NODES;
    const int E = in_sizes[1] / 2;
    const int* src = ei;
    const int* dst = ei + E;

    // ws layout (ints): R[100016] | R2[100016] | cursor[256] | dinv[100016] |
    //                   eidx[NBUCK*CAP] | packed[NBUCK*CAP] | g1[16N] | g2[16N] | part[64N]
    int* R      = (int*)d_ws;
    int* R2     = R + 100016;
    int* cursor = R2 + 100016;
    float* dinv = (float*)(cursor + 256);
    int* eidx   = (int*)(dinv + 100016);
    int* packed = eidx + NBUCK * CAP;
    float* g1   = (float*)(packed + NBUCK * CAP);
    float* g2   = g1 + 16 * N;
    float* part = g2 + 16 * N;

    const int NB = (N + 255) / 256;               // 391
    const int NCH4 = (E + CHUNK4 - 1) / CHUNK4;   // 782 @ E=3.2M

    hipMemsetAsync(cursor, 0, NBUCK * sizeof(int), stream);
    k1_kernel<<<NCH4 + NB * KSPLIT, 256, 0, stream>>>(src, dst, cursor, packed,
                                                      x, W1, part, E, N, NCH4);
    k2_kernel<<<NBUCK + (N * H_DIM / 4 + 1023) / 1024, 1024, 0, stream>>>(
        cursor, packed, R, R2, dinv, eidx, part, g1, N);
    agg1_kernel<<<(N * 16 + 255) / 256, 256, 0, stream>>>(R, R2, eidx, g1, dinv, b1, g2, N);
    fin2_kernel<<<N / 16, 256, 0, stream>>>(R, R2, eidx, g2, dinv, W2, b2, out, N);
}